// Round 11
// baseline (393.634 us; speedup 1.0000x reference)
//
#include <hip/hip_runtime.h>
#include <hip/hip_bf16.h>
#include <math.h>

#define C_DIM 192
#define NTOK 16384
#define NB 16
#define NH 8
#define HD 24
#define EPSN 1e-12f

typedef float f32x4 __attribute__((ext_vector_type(4)));
typedef __bf16 bf16x4 __attribute__((ext_vector_type(4)));
typedef __bf16 bf16x8 __attribute__((ext_vector_type(8)));

__device__ __forceinline__ f32x4 mfma16(bf16x8 a, bf16x8 b, f32x4 c) {
  return __builtin_amdgcn_mfma_f32_16x16x32_bf16(a, b, c, 0, 0, 0);
}

// load 8 consecutive f32 (16B-aligned x2) and convert to 8 bf16
__device__ __forceinline__ bf16x8 cvt8(const float* __restrict__ p) {
  f32x4 a = *(const f32x4*)p;
  f32x4 b = *(const f32x4*)(p + 4);
  bf16x8 r;
  r[0] = (__bf16)a[0]; r[1] = (__bf16)a[1]; r[2] = (__bf16)a[2]; r[3] = (__bf16)a[3];
  r[4] = (__bf16)b[0]; r[5] = (__bf16)b[1]; r[6] = (__bf16)b[2]; r[7] = (__bf16)b[3];
  return r;
}

// ---------------- K1 v6: partial Gram, NO LDS, NO barriers ------------------
// K3-recipe transplant: fragments built straight from global via cvt8 (R0's
// proven indexing). Per-slab block working set = 24KB -> L1-served reuse
// (each row window read by 2 fa-waves + 2 fb-waves; waves 0/3 have fa==fb).
// Manual 2x unroll, alternating register sets: loads(s+1) issue before
// MFMAs(s), no barrier ever.
__global__ __launch_bounds__(256, 2) void k1_gram(const float* __restrict__ x,
                                                  float* __restrict__ gpart,
                                                  int kc) {
  const int b = blockIdx.y, chunk = blockIdx.x;
  const float* xb = x + (size_t)b * C_DIM * NTOK + (size_t)chunk * kc;
  const int lane = threadIdx.x & 63, wid = threadIdx.x >> 6;
  const int lrow = lane & 15, loct = lane >> 4;
  const int r0 = (wid >> 1) * 96, c0 = (wid & 1) * 96;
  const float* pA = xb + (size_t)(r0 + lrow) * NTOK + 8 * loct;
  const float* pB = xb + (size_t)(c0 + lrow) * NTOK + 8 * loct;
  f32x4 acc[6][6] = {};
  bf16x8 fa0[6], fb0[6], fa1[6], fb1[6];

#define K1_LOAD(fa_, fb_, ks)                                                  \
  {                                                                            \
    _Pragma("unroll") for (int i = 0; i < 6; ++i)                              \
        fa_[i] = cvt8(pA + (size_t)(16 * i) * NTOK + (ks));                    \
    _Pragma("unroll") for (int j = 0; j < 6; ++j)                              \
        fb_[j] = cvt8(pB + (size_t)(16 * j) * NTOK + (ks));                    \
  }
#define K1_MFMA(fa_, fb_)                                                      \
  {                                                                            \
    _Pragma("unroll") for (int j = 0; j < 6; ++j)                              \
        _Pragma("unroll") for (int i = 0; i < 6; ++i)                          \
            acc[i][j] = mfma16(fa_[i], fb_[j], acc[i][j]);                     \
  }

  K1_LOAD(fa0, fb0, 0);
  for (int ks = 0; ks < kc; ks += 64) {
    if (ks + 32 < kc) K1_LOAD(fa1, fb1, ks + 32);
    K1_MFMA(fa0, fb0);
    if (ks + 64 < kc) K1_LOAD(fa0, fb0, ks + 64);
    K1_MFMA(fa1, fb1);
  }
#undef K1_LOAD
#undef K1_MFMA

  float* gp = gpart + ((size_t)chunk * NB + b) * C_DIM * C_DIM;
#pragma unroll
  for (int i = 0; i < 6; ++i)
#pragma unroll
    for (int j = 0; j < 6; ++j)
#pragma unroll
      for (int e = 0; e < 4; ++e)
        gp[(size_t)(r0 + 16 * i + 4 * loct + e) * C_DIM + (c0 + 16 * j + lrow)] =
            acc[i][j][e];
}

// ---------------- K2a: reduce partials -> G ---------------------------------
__global__ __launch_bounds__(256) void k2a_reduce(const float* __restrict__ gpart,
                                                  float* __restrict__ G,
                                                  int nchunk) {
  const size_t total = (size_t)NB * C_DIM * C_DIM;
  size_t e0 = ((size_t)blockIdx.x * 256 + threadIdx.x) * 4;
  f32x4 s = {};
  for (int c = 0; c < nchunk; ++c) s += *(const f32x4*)(gpart + c * total + e0);
  *(f32x4*)(G + e0) = s;
}

// ---------------- K2b1: Tt[b] = [Wq|Wk]^T @ G  (384x192), uses G symmetry ---
__global__ __launch_bounds__(256) void k2b1_t(const float* __restrict__ G,
                                              const float* __restrict__ wqkv,
                                              float* __restrict__ Tt) {
  const int b = blockIdx.y, rb = blockIdx.x;  // rb 0..5 -> 64 rows
  const int lane = threadIdx.x & 63, wid = threadIdx.x >> 6;
  const int lrow = lane & 15, loct = lane >> 4;
  const float* Gb = G + (size_t)b * C_DIM * C_DIM;
  const int ddA = rb * 64 + wid * 16 + lrow;  // < 384, == wqkv column index
  f32x4 acc[12] = {};
  for (int s = 0; s < 6; ++s) {
    bf16x8 fa;
#pragma unroll
    for (int e = 0; e < 8; ++e)
      fa[e] = (__bf16)wqkv[(size_t)(32 * s + 8 * loct + e) * 576 + ddA];
#pragma unroll
    for (int j = 0; j < 12; ++j) {
      bf16x8 fb = cvt8(Gb + (size_t)(16 * j + lrow) * C_DIM + 32 * s + 8 * loct);
      acc[j] = mfma16(fa, fb, acc[j]);
    }
  }
  float* To = Tt + (size_t)b * 384 * C_DIM;
#pragma unroll
  for (int j = 0; j < 12; ++j)
#pragma unroll
    for (int e = 0; e < 4; ++e)
      To[(size_t)(rb * 64 + wid * 16 + 4 * loct + e) * C_DIM + 16 * j + lrow] =
          acc[j][e];
}

// ---------------- K2b2: per (b,h): S, norms, softmax, Yt -------------------
__global__ __launch_bounds__(256) void k2b2_attn(const float* __restrict__ Tt,
                                                 const float* __restrict__ wqkv,
                                                 const float* __restrict__ temp,
                                                 float* __restrict__ Yt) {
  const int b = blockIdx.y, h = blockIdx.x;
  __shared__ float SL[32][33];
  __shared__ float qn2L[HD], kn2L[HD];
  const int t = threadIdx.x;
  const int lane = t & 63, wid = t >> 6;
  const int lrow = lane & 15, loct = lane >> 4;
  const float* Tb = Tt + (size_t)b * 384 * C_DIM;
  const int r = wid >> 1, j = wid & 1;  // 2x2 tiles cover 32x32 (clip to 24x24)
  f32x4 acc = {};
  for (int s = 0; s < 6; ++s) {
    bf16x8 fa = cvt8(Tb + (size_t)(h * HD + 16 * r + lrow) * C_DIM + 32 * s + 8 * loct);
    bf16x8 fb;
#pragma unroll
    for (int e = 0; e < 8; ++e)
      fb[e] = (__bf16)wqkv[(size_t)(32 * s + 8 * loct + e) * 576 + 192 + h * HD +
                           16 * j + lrow];
    acc = mfma16(fa, fb, acc);
  }
#pragma unroll
  for (int e = 0; e < 4; ++e) {
    int d = 16 * r + 4 * loct + e, ee = 16 * j + lrow;
    if (d < HD && ee < HD) SL[d][ee] = acc[e];
  }
  if (t < 48) {  // squared norms: diag of Wq^T G Wq / Wk^T G Wk
    const int dd = (t < 24) ? t : t - 24;
    const int row = ((t < 24) ? 0 : 192) + h * HD + dd;
    float s = 0.f;
    for (int c = 0; c < C_DIM; ++c)
      s += Tb[(size_t)row * C_DIM + c] * wqkv[(size_t)c * 576 + row];
    if (t < 24) qn2L[dd] = s; else kn2L[dd] = s;
  }
  __syncthreads();
  if (t < HD) {  // softmax row t
    const float tp = temp[h];
    float nq = fmaxf(sqrtf(fmaxf(qn2L[t], 0.f)), EPSN);
    float lg[HD];
    float m = -1e30f;
#pragma unroll
    for (int e = 0; e < HD; ++e) {
      float nk = fmaxf(sqrtf(fmaxf(kn2L[e], 0.f)), EPSN);
      lg[e] = SL[t][e] / (nq * nk) * tp;
      m = fmaxf(m, lg[e]);
    }
    float sum = 0.f;
#pragma unroll
    for (int e = 0; e < HD; ++e) { lg[e] = __expf(lg[e] - m); sum += lg[e]; }
    float inv = 1.f / sum;
#pragma unroll
    for (int e = 0; e < HD; ++e) SL[t][e] = lg[e] * inv;
  }
  __syncthreads();
  if (t < C_DIM) {  // Yt[b][ci=t][h*24+d] = sum_e attn[d][e] * Wv[t][e]
    float wv[HD];
#pragma unroll
    for (int e = 0; e < HD; ++e)
      wv[e] = wqkv[(size_t)t * 576 + 384 + h * HD + e];
    float* Yo = Yt + ((size_t)b * C_DIM + t) * C_DIM + h * HD;
#pragma unroll
    for (int d = 0; d < HD; ++d) {
      float y = 0.f;
#pragma unroll
      for (int e = 0; e < HD; ++e) y += SL[d][e] * wv[e];
      Yo[d] = y;
    }
  }
}

// ---------------- K2c: M[b] = Wproj^T @ Y  (bf16 out) -----------------------
__global__ __launch_bounds__(256) void k2c_m(const float* __restrict__ wproj,
                                             const float* __restrict__ Yt,
                                             __bf16* __restrict__ M) {
  const int b = blockIdx.y, rb = blockIdx.x;  // rb 0..2 -> 64 rows
  const int lane = threadIdx.x & 63, wid = threadIdx.x >> 6;
  const int lrow = lane & 15, loct = lane >> 4;
  const float* Yb = Yt + (size_t)b * C_DIM * C_DIM;
  const int coA = rb * 64 + wid * 16 + lrow;
  f32x4 acc[12] = {};
  for (int s = 0; s < 6; ++s) {
    bf16x8 fa;
#pragma unroll
    for (int e = 0; e < 8; ++e)
      fa[e] = (__bf16)wproj[(size_t)(32 * s + 8 * loct + e) * C_DIM + coA];
#pragma unroll
    for (int j = 0; j < 12; ++j) {
      bf16x8 fb = cvt8(Yb + (size_t)(16 * j + lrow) * C_DIM + 32 * s + 8 * loct);
      acc[j] = mfma16(fa, fb, acc[j]);
    }
  }
  __bf16* Mo = M + (size_t)b * C_DIM * C_DIM;
#pragma unroll
  for (int j = 0; j < 12; ++j)
#pragma unroll
    for (int e = 0; e < 4; ++e)
      Mo[(size_t)(rb * 64 + wid * 16 + 4 * loct + e) * C_DIM + 16 * j + lrow] =
          (__bf16)acc[j][e];
}

// ---------------- K3 v6 (proven 95us): out[b] = M[b] @ x[b] + bias ----------
// Token-interleaved fragments; half-M in 36.8KB swizzled LDS; f32x4 x loads;
// per-wave LDS transpose epilogue -> dwordx4 store runs.
__global__ __launch_bounds__(256, 3) void k3_out(const float* __restrict__ x,
                                                 const __bf16* __restrict__ M,
                                                 const float* __restrict__ bproj,
                                                 float* __restrict__ out) {
  const int nt = blockIdx.x, half = blockIdx.y, b = blockIdx.z;
  const int rbase = half * 96;
  __shared__ __bf16 Ml[96 * C_DIM];  // 36864B; overlaid by epi after main loop
  __shared__ float biasL[96];
  const int t = threadIdx.x;
  const int lane = t & 63, w = t >> 6;
  const int lrow = lane & 15, loct = lane >> 4;

  const __bf16* Mb = M + (size_t)b * C_DIM * C_DIM + (size_t)rbase * C_DIM;
  for (int i = t; i < 96 * 24; i += 256) {
    int row = i / 24, ch = i % 24;
    bf16x8 v = *(const bf16x8*)(Mb + row * C_DIM + ch * 8);
    *(bf16x8*)(Ml + row * C_DIM + ((ch ^ (row & 7)) * 8)) = v;
  }
  if (t < 96) biasL[t] = bproj[rbase + t];
  __syncthreads();

  const float* xb = x + (size_t)b * C_DIM * NTOK;
  float* ob = out + (size_t)b * C_DIM * NTOK;
  const int n0 = nt * 256 + w * 64;  // wave's 64-token window

  f32x4 acc[6][4] = {};
  f32x4 xs4[8];  // prefetch: slab's 8 channels x 4 consecutive tokens
#pragma unroll
  for (int e = 0; e < 8; ++e)
    xs4[e] = *(const f32x4*)(xb + (size_t)(8 * loct + e) * NTOK + n0 + 4 * lrow);

  for (int s = 0; s < 6; ++s) {
    bf16x8 fb[4];  // fb[nf][e] = x[ch=32s+8loct+e][tok=n0+4*lrow+nf]
#pragma unroll
    for (int nf = 0; nf < 4; ++nf)
#pragma unroll
      for (int e = 0; e < 8; ++e)
        fb[nf][e] = (__bf16)xs4[e][nf];
    if (s < 5) {
#pragma unroll
      for (int e = 0; e < 8; ++e)
        xs4[e] = *(const f32x4*)(xb + (size_t)(32 * (s + 1) + 8 * loct + e) * NTOK +
                                 n0 + 4 * lrow);
    }
#pragma unroll
    for (int tt = 0; tt < 6; ++tt) {
      int rowb = 16 * tt + lrow;
      bf16x8 fa = *(const bf16x8*)(Ml + rowb * C_DIM +
                                   (((4 * s + loct) ^ (rowb & 7)) * 8));
#pragma unroll
      for (int nf = 0; nf < 4; ++nf)
        acc[tt][nf] = mfma16(fa, fb[nf], acc[tt][nf]);
    }
  }

  __syncthreads();  // all waves done reading Ml; safe to overlay epi
  // per-wave transpose buffer: 16 rows x 64 tokens, stride 68 f32
  float* epi_w = (float*)Ml + w * 1088;
#pragma unroll
  for (int tt = 0; tt < 6; ++tt) {
    f32x4 bias4 = *(const f32x4*)(biasL + 16 * tt + 4 * loct);  // rows 4loct+e
#pragma unroll
    for (int e = 0; e < 4; ++e) {
      f32x4 v;
      v[0] = acc[tt][0][e] + bias4[e];
      v[1] = acc[tt][1][e] + bias4[e];
      v[2] = acc[tt][2][e] + bias4[e];
      v[3] = acc[tt][3][e] + bias4[e];  // tokens 4*lrow+0..3 of row 16tt+4loct+e
      *(f32x4*)(epi_w + (4 * loct + e) * 68 + 4 * lrow) = v;
    }
    // wave-local ds_write -> ds_read ordered by program order, no barrier
#pragma unroll
    for (int h = 0; h < 4; ++h) {
      int r = 4 * h + loct;
      f32x4 v = *(const f32x4*)(epi_w + r * 68 + 4 * lrow);
      *(f32x4*)(ob + (size_t)(rbase + 16 * tt + r) * NTOK + n0 + 4 * lrow) = v;
    }
  }
}

extern "C" void kernel_launch(void* const* d_in, const int* in_sizes, int n_in,
                              void* d_out, int out_size, void* d_ws, size_t ws_size,
                              hipStream_t stream) {
  const float* x = (const float*)d_in[0];
  const float* wqkv = (const float*)d_in[1];
  const float* wproj = (const float*)d_in[2];
  const float* bproj = (const float*)d_in[3];
  const float* temp = (const float*)d_in[4];
  float* out = (float*)d_out;

  const size_t GSZ = (size_t)NB * C_DIM * C_DIM;  // 589824 floats
  const size_t TSZ = (size_t)NB * 384 * C_DIM;    // 1179648 floats
  int nchunk = 32;
  while (nchunk > 1 &&
         ((size_t)nchunk * GSZ + GSZ + TSZ + GSZ + GSZ) * 4 > ws_size)
    nchunk >>= 1;
  float* wsf = (float*)d_ws;
  float* gpart = wsf;
  float* G = gpart + (size_t)nchunk * GSZ;
  float* Tt = G + GSZ;
  float* Yt = Tt + TSZ;
  __bf16* M = (__bf16*)(Yt + GSZ);

  k1_gram<<<dim3(nchunk, NB), 256, 0, stream>>>(x, gpart, NTOK / nchunk);
  k2a_reduce<<<dim3(576), 256, 0, stream>>>(gpart, G, nchunk);
  k2b1_t<<<dim3(6, NB), 256, 0, stream>>>(G, wqkv, Tt);
  k2b2_attn<<<dim3(NH, NB), 256, 0, stream>>>(Tt, wqkv, temp, Yt);
  k2c_m<<<dim3(3, NB), 256, 0, stream>>>(wproj, Yt, M);
  k3_out<<<dim3(NTOK / 256, 2, NB), 256, 0, stream>>>(x, M, bproj, out);
}

// Round 12
// 262.326 us; speedup vs baseline: 1.5006x; 1.5006x over previous
//
#include <hip/hip_runtime.h>
#include <hip/hip_bf16.h>
#include <math.h>

#define C_DIM 192
#define NTOK 16384
#define NB 16
#define NH 8
#define HD 24
#define EPSN 1e-12f

typedef float f32x4 __attribute__((ext_vector_type(4)));
typedef __bf16 bf16x4 __attribute__((ext_vector_type(4)));
typedef __bf16 bf16x8 __attribute__((ext_vector_type(8)));

__device__ __forceinline__ f32x4 mfma16(bf16x8 a, bf16x8 b, f32x4 c) {
  return __builtin_amdgcn_mfma_f32_16x16x32_bf16(a, b, c, 0, 0, 0);
}

// load 8 consecutive f32 (16B-aligned x2) and convert to 8 bf16
__device__ __forceinline__ bf16x8 cvt8(const float* __restrict__ p) {
  f32x4 a = *(const f32x4*)p;
  f32x4 b = *(const f32x4*)(p + 4);
  bf16x8 r;
  r[0] = (__bf16)a[0]; r[1] = (__bf16)a[1]; r[2] = (__bf16)a[2]; r[3] = (__bf16)a[3];
  r[4] = (__bf16)b[0]; r[5] = (__bf16)b[1]; r[6] = (__bf16)b[2]; r[7] = (__bf16)b[3];
  return r;
}

// ---------------- K1: partial Gram + token-major bf16 echo ------------------
// R2-proven staging (stride-40 LDS dbuf) + per-step transpose buffer Tb
// (token-major, 16B-chunk XOR swizzle) emitted to xe[b][tok][ch] bf16.
// Same barrier count as before: Tb[nxt] written with xsh[nxt], Tb[cur]
// emitted after the barrier that published it.
__global__ __launch_bounds__(256, 2) void k1_gram(const float* __restrict__ x,
                                                  float* __restrict__ gpart,
                                                  __bf16* __restrict__ xe,
                                                  int kc) {
  const int b = blockIdx.y, chunk = blockIdx.x;
  const float* xb = x + (size_t)b * C_DIM * NTOK + (size_t)chunk * kc;
  __shared__ __bf16 xsh[2][C_DIM * 40];   // 2 x 15KB channel-major
  __shared__ __bf16 tb[2][32 * C_DIM];    // 2 x 12KB token-major (swizzled)
  const int t = threadIdx.x;
  const int lane = t & 63, wid = t >> 6;
  const int lrow = lane & 15, loct = lane >> 4;
  const int r0 = (wid >> 1) * 96, c0 = (wid & 1) * 96;
  const int etok = t >> 3, eseg = t & 7;  // echo readback: token, 24ch-segment
  __bf16* xe_b = xe + ((size_t)b * NTOK + (size_t)chunk * kc) * C_DIM;
  f32x4 acc[6][6] = {};
  f32x4 stg[6];

#define K1_LOADR(ks_)                                                          \
  {                                                                            \
    _Pragma("unroll") for (int it = 0; it < 6; ++it) {                         \
      int idx = it * 256 + t, r = idx >> 3, c8 = idx & 7;                      \
      stg[it] = *(const f32x4*)(xb + (size_t)r * NTOK + (ks_) + 4 * c8);       \
    }                                                                          \
  }
#define K1_WRITE(buf)                                                          \
  {                                                                            \
    _Pragma("unroll") for (int it = 0; it < 6; ++it) {                         \
      int idx = it * 256 + t, r = idx >> 3, c8 = idx & 7;                      \
      bf16x4 w;                                                                \
      w[0] = (__bf16)stg[it][0]; w[1] = (__bf16)stg[it][1];                    \
      w[2] = (__bf16)stg[it][2]; w[3] = (__bf16)stg[it][3];                    \
      *(bf16x4*)(&xsh[buf][r * 40 + 4 * c8]) = w;                              \
      _Pragma("unroll") for (int jj = 0; jj < 4; ++jj) {                       \
        int tok = 4 * c8 + jj;                                                 \
        tb[buf][tok * C_DIM + ((((r >> 3) ^ (tok & 7)) << 3) | (r & 7))] =     \
            w[jj];                                                             \
      }                                                                        \
    }                                                                          \
  }
#define K1_EMIT(buf, ks_)                                                      \
  {                                                                            \
    _Pragma("unroll") for (int j = 0; j < 3; ++j) {                            \
      int chk = 3 * eseg + j;                                                  \
      bf16x8 v = *(const bf16x8*)&tb[buf][etok * C_DIM +                       \
                                          ((chk ^ (etok & 7)) << 3)];          \
      *(bf16x8*)(xe_b + (size_t)((ks_) + etok) * C_DIM + chk * 8) = v;         \
    }                                                                          \
  }
#define K1_COMP(buf)                                                           \
  {                                                                            \
    bf16x8 fa[6];                                                              \
    _Pragma("unroll") for (int i = 0; i < 6; ++i)                              \
        fa[i] = *(const bf16x8*)(&xsh[buf][(r0 + 16 * i + lrow) * 40 +         \
                                           8 * loct]);                         \
    _Pragma("unroll") for (int j = 0; j < 6; ++j) {                            \
      bf16x8 fb =                                                              \
          *(const bf16x8*)(&xsh[buf][(c0 + 16 * j + lrow) * 40 + 8 * loct]);   \
      _Pragma("unroll") for (int i = 0; i < 6; ++i)                            \
          acc[i][j] = mfma16(fa[i], fb, acc[i][j]);                            \
    }                                                                          \
  }

  K1_LOADR(0);
  K1_WRITE(0);
  __syncthreads();

  for (int ks = 0; ks < kc; ks += 32) {
    const int cur = (ks >> 5) & 1;
    const bool more = (ks + 32) < kc;
    if (more) K1_LOADR(ks + 32);
    K1_EMIT(cur, ks);   // echo the slab published by the last barrier
    K1_COMP(cur);
    if (more) K1_WRITE(cur ^ 1);
    __syncthreads();
  }
#undef K1_LOADR
#undef K1_WRITE
#undef K1_EMIT
#undef K1_COMP

  float* gp = gpart + ((size_t)chunk * NB + b) * C_DIM * C_DIM;
#pragma unroll
  for (int i = 0; i < 6; ++i)
#pragma unroll
    for (int j = 0; j < 6; ++j)
#pragma unroll
      for (int e = 0; e < 4; ++e)
        gp[(size_t)(r0 + 16 * i + 4 * loct + e) * C_DIM + (c0 + 16 * j + lrow)] =
            acc[i][j][e];
}

// ---------------- K2a: reduce partials -> G ---------------------------------
__global__ __launch_bounds__(256) void k2a_reduce(const float* __restrict__ gpart,
                                                  float* __restrict__ G,
                                                  int nchunk) {
  const size_t total = (size_t)NB * C_DIM * C_DIM;
  size_t e0 = ((size_t)blockIdx.x * 256 + threadIdx.x) * 4;
  f32x4 s = {};
  for (int c = 0; c < nchunk; ++c) s += *(const f32x4*)(gpart + c * total + e0);
  *(f32x4*)(G + e0) = s;
}

// ---------------- K2b1: Tt[b] = [Wq|Wk]^T @ G  (384x192), uses G symmetry ---
__global__ __launch_bounds__(256) void k2b1_t(const float* __restrict__ G,
                                              const float* __restrict__ wqkv,
                                              float* __restrict__ Tt) {
  const int b = blockIdx.y, rb = blockIdx.x;  // rb 0..5 -> 64 rows
  const int lane = threadIdx.x & 63, wid = threadIdx.x >> 6;
  const int lrow = lane & 15, loct = lane >> 4;
  const float* Gb = G + (size_t)b * C_DIM * C_DIM;
  const int ddA = rb * 64 + wid * 16 + lrow;  // < 384, == wqkv column index
  f32x4 acc[12] = {};
  for (int s = 0; s < 6; ++s) {
    bf16x8 fa;
#pragma unroll
    for (int e = 0; e < 8; ++e)
      fa[e] = (__bf16)wqkv[(size_t)(32 * s + 8 * loct + e) * 576 + ddA];
#pragma unroll
    for (int j = 0; j < 12; ++j) {
      bf16x8 fb = cvt8(Gb + (size_t)(16 * j + lrow) * C_DIM + 32 * s + 8 * loct);
      acc[j] = mfma16(fa, fb, acc[j]);
    }
  }
  float* To = Tt + (size_t)b * 384 * C_DIM;
#pragma unroll
  for (int j = 0; j < 12; ++j)
#pragma unroll
    for (int e = 0; e < 4; ++e)
      To[(size_t)(rb * 64 + wid * 16 + 4 * loct + e) * C_DIM + 16 * j + lrow] =
          acc[j][e];
}

// ---------------- K2b2: per (b,h): S, norms, softmax, Yt -------------------
__global__ __launch_bounds__(256) void k2b2_attn(const float* __restrict__ Tt,
                                                 const float* __restrict__ wqkv,
                                                 const float* __restrict__ temp,
                                                 float* __restrict__ Yt) {
  const int b = blockIdx.y, h = blockIdx.x;
  __shared__ float SL[32][33];
  __shared__ float qn2L[HD], kn2L[HD];
  const int t = threadIdx.x;
  const int lane = t & 63, wid = t >> 6;
  const int lrow = lane & 15, loct = lane >> 4;
  const float* Tb = Tt + (size_t)b * 384 * C_DIM;
  const int r = wid >> 1, j = wid & 1;  // 2x2 tiles cover 32x32 (clip to 24x24)
  f32x4 acc = {};
  for (int s = 0; s < 6; ++s) {
    bf16x8 fa = cvt8(Tb + (size_t)(h * HD + 16 * r + lrow) * C_DIM + 32 * s + 8 * loct);
    bf16x8 fb;
#pragma unroll
    for (int e = 0; e < 8; ++e)
      fb[e] = (__bf16)wqkv[(size_t)(32 * s + 8 * loct + e) * 576 + 192 + h * HD +
                           16 * j + lrow];
    acc = mfma16(fa, fb, acc);
  }
#pragma unroll
  for (int e = 0; e < 4; ++e) {
    int d = 16 * r + 4 * loct + e, ee = 16 * j + lrow;
    if (d < HD && ee < HD) SL[d][ee] = acc[e];
  }
  if (t < 48) {  // squared norms: diag of Wq^T G Wq / Wk^T G Wk
    const int dd = (t < 24) ? t : t - 24;
    const int row = ((t < 24) ? 0 : 192) + h * HD + dd;
    float s = 0.f;
    for (int c = 0; c < C_DIM; ++c)
      s += Tb[(size_t)row * C_DIM + c] * wqkv[(size_t)c * 576 + row];
    if (t < 24) qn2L[dd] = s; else kn2L[dd] = s;
  }
  __syncthreads();
  if (t < HD) {  // softmax row t
    const float tp = temp[h];
    float nq = fmaxf(sqrtf(fmaxf(qn2L[t], 0.f)), EPSN);
    float lg[HD];
    float m = -1e30f;
#pragma unroll
    for (int e = 0; e < HD; ++e) {
      float nk = fmaxf(sqrtf(fmaxf(kn2L[e], 0.f)), EPSN);
      lg[e] = SL[t][e] / (nq * nk) * tp;
      m = fmaxf(m, lg[e]);
    }
    float sum = 0.f;
#pragma unroll
    for (int e = 0; e < HD; ++e) { lg[e] = __expf(lg[e] - m); sum += lg[e]; }
    float inv = 1.f / sum;
#pragma unroll
    for (int e = 0; e < HD; ++e) SL[t][e] = lg[e] * inv;
  }
  __syncthreads();
  if (t < C_DIM) {  // Yt[b][ci=t][h*24+d] = sum_e attn[d][e] * Wv[t][e]
    float wv[HD];
#pragma unroll
    for (int e = 0; e < HD; ++e)
      wv[e] = wqkv[(size_t)t * 576 + 384 + h * HD + e];
    float* Yo = Yt + ((size_t)b * C_DIM + t) * C_DIM + h * HD;
#pragma unroll
    for (int d = 0; d < HD; ++d) {
      float y = 0.f;
#pragma unroll
      for (int e = 0; e < HD; ++e) y += SL[d][e] * wv[e];
      Yo[d] = y;
    }
  }
}

// ---------------- K2c: M[b] = Wproj^T @ Y  (bf16 out) -----------------------
__global__ __launch_bounds__(256) void k2c_m(const float* __restrict__ wproj,
                                             const float* __restrict__ Yt,
                                             __bf16* __restrict__ M) {
  const int b = blockIdx.y, rb = blockIdx.x;  // rb 0..2 -> 64 rows
  const int lane = threadIdx.x & 63, wid = threadIdx.x >> 6;
  const int lrow = lane & 15, loct = lane >> 4;
  const float* Yb = Yt + (size_t)b * C_DIM * C_DIM;
  const int coA = rb * 64 + wid * 16 + lrow;
  f32x4 acc[12] = {};
  for (int s = 0; s < 6; ++s) {
    bf16x8 fa;
#pragma unroll
    for (int e = 0; e < 8; ++e)
      fa[e] = (__bf16)wproj[(size_t)(32 * s + 8 * loct + e) * C_DIM + coA];
#pragma unroll
    for (int j = 0; j < 12; ++j) {
      bf16x8 fb = cvt8(Yb + (size_t)(16 * j + lrow) * C_DIM + 32 * s + 8 * loct);
      acc[j] = mfma16(fa, fb, acc[j]);
    }
  }
  __bf16* Mo = M + (size_t)b * C_DIM * C_DIM;
#pragma unroll
  for (int j = 0; j < 12; ++j)
#pragma unroll
    for (int e = 0; e < 4; ++e)
      Mo[(size_t)(rb * 64 + wid * 16 + 4 * loct + e) * C_DIM + 16 * j + lrow] =
          (__bf16)acc[j][e];
}

// ---------------- K3 v9: out[b] = M[b] @ xe[b] + bias -----------------------
// v6 structure, x loads replaced by token-major echo reads: per slab, 4
// bf16x8 loads/lane; each 64B line = one token's full 32-ch slab, consumed
// entirely within the block -> DRAM-page-local. No f32->bf16 cvt in loop.
__global__ __launch_bounds__(256, 3) void k3_out(const __bf16* __restrict__ xe,
                                                 const __bf16* __restrict__ M,
                                                 const float* __restrict__ bproj,
                                                 float* __restrict__ out) {
  const int nt = blockIdx.x, half = blockIdx.y, b = blockIdx.z;
  const int rbase = half * 96;
  __shared__ __bf16 Ml[96 * C_DIM];  // 36864B; overlaid by epi after main loop
  __shared__ float biasL[96];
  const int t = threadIdx.x;
  const int lane = t & 63, w = t >> 6;
  const int lrow = lane & 15, loct = lane >> 4;

  const __bf16* Mb = M + (size_t)b * C_DIM * C_DIM + (size_t)rbase * C_DIM;
  for (int i = t; i < 96 * 24; i += 256) {
    int row = i / 24, ch = i % 24;
    bf16x8 v = *(const bf16x8*)(Mb + row * C_DIM + ch * 8);
    *(bf16x8*)(Ml + row * C_DIM + ((ch ^ (row & 7)) * 8)) = v;
  }
  if (t < 96) biasL[t] = bproj[rbase + t];
  __syncthreads();

  const __bf16* xeb = xe + (size_t)b * NTOK * C_DIM;
  float* ob = out + (size_t)b * C_DIM * NTOK;
  const int n0 = nt * 256 + w * 64;  // wave's 64-token window

  f32x4 acc[6][4] = {};
  bf16x8 xs8[4];  // prefetch: 4 tokens x (8 ch of the slab)
#pragma unroll
  for (int nf = 0; nf < 4; ++nf)
    xs8[nf] = *(const bf16x8*)(xeb + (size_t)(n0 + 4 * lrow + nf) * C_DIM +
                               8 * loct);

  for (int s = 0; s < 6; ++s) {
    bf16x8 fb[4];
#pragma unroll
    for (int nf = 0; nf < 4; ++nf) fb[nf] = xs8[nf];
    if (s < 5) {
#pragma unroll
      for (int nf = 0; nf < 4; ++nf)
        xs8[nf] = *(const bf16x8*)(xeb + (size_t)(n0 + 4 * lrow + nf) * C_DIM +
                                   32 * (s + 1) + 8 * loct);
    }
#pragma unroll
    for (int tt = 0; tt < 6; ++tt) {
      int rowb = 16 * tt + lrow;
      bf16x8 fa = *(const bf16x8*)(Ml + rowb * C_DIM +
                                   (((4 * s + loct) ^ (rowb & 7)) * 8));
#pragma unroll
      for (int nf = 0; nf < 4; ++nf)
        acc[tt][nf] = mfma16(fa, fb[nf], acc[tt][nf]);
    }
  }

  __syncthreads();  // all waves done reading Ml; safe to overlay epi
  // per-wave transpose buffer: 16 rows x 64 tokens, stride 68 f32
  float* epi_w = (float*)Ml + w * 1088;
#pragma unroll
  for (int tt = 0; tt < 6; ++tt) {
    f32x4 bias4 = *(const f32x4*)(biasL + 16 * tt + 4 * loct);  // rows 4loct+e
#pragma unroll
    for (int e = 0; e < 4; ++e) {
      f32x4 v;
      v[0] = acc[tt][0][e] + bias4[e];
      v[1] = acc[tt][1][e] + bias4[e];
      v[2] = acc[tt][2][e] + bias4[e];
      v[3] = acc[tt][3][e] + bias4[e];  // tokens 4*lrow+0..3 of row 16tt+4loct+e
      *(f32x4*)(epi_w + (4 * loct + e) * 68 + 4 * lrow) = v;
    }
    // wave-local ds_write -> ds_read ordered by program order, no barrier
#pragma unroll
    for (int h = 0; h < 4; ++h) {
      int r = 4 * h + loct;
      f32x4 v = *(const f32x4*)(epi_w + r * 68 + 4 * lrow);
      *(f32x4*)(ob + (size_t)(rbase + 16 * tt + r) * NTOK + n0 + 4 * lrow) = v;
    }
  }
}

extern "C" void kernel_launch(void* const* d_in, const int* in_sizes, int n_in,
                              void* d_out, int out_size, void* d_ws, size_t ws_size,
                              hipStream_t stream) {
  const float* x = (const float*)d_in[0];
  const float* wqkv = (const float*)d_in[1];
  const float* wproj = (const float*)d_in[2];
  const float* bproj = (const float*)d_in[3];
  const float* temp = (const float*)d_in[4];
  float* out = (float*)d_out;

  const size_t XB = (size_t)NB * NTOK * C_DIM;    // echo elems (100.7 MB bf16)
  const size_t GSZ = (size_t)NB * C_DIM * C_DIM;  // 589824 floats
  const size_t TSZ = (size_t)NB * 384 * C_DIM;    // 1179648 floats
  int nchunk = 32;
  while (nchunk > 1 &&
         XB * 2 + ((size_t)nchunk * GSZ + GSZ + TSZ + GSZ + GSZ) * 4 > ws_size)
    nchunk >>= 1;
  __bf16* xe = (__bf16*)d_ws;
  float* wsf = (float*)d_ws + XB / 2;
  float* gpart = wsf;
  float* G = gpart + (size_t)nchunk * GSZ;
  float* Tt = G + GSZ;
  float* Yt = Tt + TSZ;
  __bf16* M = (__bf16*)(Yt + GSZ);

  k1_gram<<<dim3(nchunk, NB), 256, 0, stream>>>(x, gpart, xe, NTOK / nchunk);
  k2a_reduce<<<dim3(576), 256, 0, stream>>>(gpart, G, nchunk);
  k2b1_t<<<dim3(6, NB), 256, 0, stream>>>(G, wqkv, Tt);
  k2b2_attn<<<dim3(NH, NB), 256, 0, stream>>>(Tt, wqkv, temp, Yt);
  k2c_m<<<dim3(3, NB), 256, 0, stream>>>(wproj, Yt, M);
  k3_out<<<dim3(NTOK / 256, 2, NB), 256, 0, stream>>>(xe, M, bproj, out);
}

// Round 13
// 232.722 us; speedup vs baseline: 1.6914x; 1.1272x over previous
//
#include <hip/hip_runtime.h>
#include <hip/hip_bf16.h>
#include <math.h>

#define C_DIM 192
#define NTOK 16384
#define NB 16
#define NH 8
#define HD 24
#define EPSN 1e-12f

typedef float f32x4 __attribute__((ext_vector_type(4)));
typedef __bf16 bf16x4 __attribute__((ext_vector_type(4)));
typedef __bf16 bf16x8 __attribute__((ext_vector_type(8)));

__device__ __forceinline__ f32x4 mfma16(bf16x8 a, bf16x8 b, f32x4 c) {
  return __builtin_amdgcn_mfma_f32_16x16x32_bf16(a, b, c, 0, 0, 0);
}

// load 8 consecutive f32 (16B-aligned x2) and convert to 8 bf16
__device__ __forceinline__ bf16x8 cvt8(const float* __restrict__ p) {
  f32x4 a = *(const f32x4*)p;
  f32x4 b = *(const f32x4*)(p + 4);
  bf16x8 r;
  r[0] = (__bf16)a[0]; r[1] = (__bf16)a[1]; r[2] = (__bf16)a[2]; r[3] = (__bf16)a[3];
  r[4] = (__bf16)b[0]; r[5] = (__bf16)b[1]; r[6] = (__bf16)b[2]; r[7] = (__bf16)b[3];
  return r;
}

// ---------------- K1 v8: partial Gram, page-burst staging -------------------
// Single 96KB LDS tile [192 rows][256 tok] bf16, 16B-chunk XOR swizzle.
// Load phase: each wave owns 48 rows; ONE wave instruction = one row's full
// 1KB contiguous chunk (64 lanes x f32x4) -> every DRAM/L3 page visit is a
// single KB-scale burst instead of 16 interleaved 128B visits. 12 rows'
// bursts in flight per wave. Then 8 k-steps of the proven 36-MFMA tile.
__global__ __launch_bounds__(256) void k1_gram(const float* __restrict__ x,
                                               float* __restrict__ gpart,
                                               int kc) {
  const int b = blockIdx.y, chunk = blockIdx.x;
  const float* xb = x + (size_t)b * C_DIM * NTOK + (size_t)chunk * kc;
  __shared__ __bf16 xs[C_DIM * 256];  // 96KB; row stride 512B, swizzled chunks
  const int t = threadIdx.x;
  const int lane = t & 63, wid = t >> 6;
  const int lrow = lane & 15, loct = lane >> 4;
  const int r0 = (wid >> 1) * 96, c0 = (wid & 1) * 96;
  f32x4 acc[6][6] = {};

  for (int ts = 0; ts < kc; ts += 256) {
    // ---- load phase: 48 rows/wave, 1KB burst per row, 12 in flight ----
    const int rbase = wid * 48;
#pragma unroll 1
    for (int rb = 0; rb < 48; rb += 12) {
      f32x4 v[12];
#pragma unroll
      for (int i = 0; i < 12; ++i)
        v[i] = *(const f32x4*)(xb + (size_t)(rbase + rb + i) * NTOK + ts + 4 * lane);
#pragma unroll
      for (int i = 0; i < 12; ++i) {
        const int row = rbase + rb + i;
        bf16x4 w;
        w[0] = (__bf16)v[i][0]; w[1] = (__bf16)v[i][1];
        w[2] = (__bf16)v[i][2]; w[3] = (__bf16)v[i][3];
        const int q = lane >> 1, h = lane & 1;  // 16B chunk, 8B half
        *(bf16x4*)(&xs[row * 256 + ((q ^ (row & 7)) * 8) + h * 4]) = w;
      }
    }
    __syncthreads();
    // ---- compute: 8 k-steps x (12 frag reads + 36 MFMA) ----
#pragma unroll
    for (int kk = 0; kk < 8; ++kk) {
      bf16x8 fa[6];
#pragma unroll
      for (int i = 0; i < 6; ++i) {
        const int row = r0 + 16 * i + lrow;
        fa[i] = *(const bf16x8*)(&xs[row * 256 +
                                     (((4 * kk + loct) ^ (row & 7)) * 8)]);
      }
#pragma unroll
      for (int j = 0; j < 6; ++j) {
        const int row = c0 + 16 * j + lrow;
        bf16x8 fb = *(const bf16x8*)(&xs[row * 256 +
                                         (((4 * kk + loct) ^ (row & 7)) * 8)]);
#pragma unroll
        for (int i = 0; i < 6; ++i) acc[i][j] = mfma16(fa[i], fb, acc[i][j]);
      }
    }
    __syncthreads();
  }

  float* gp = gpart + ((size_t)chunk * NB + b) * C_DIM * C_DIM;
#pragma unroll
  for (int i = 0; i < 6; ++i)
#pragma unroll
    for (int j = 0; j < 6; ++j)
#pragma unroll
      for (int e = 0; e < 4; ++e)
        gp[(size_t)(r0 + 16 * i + 4 * loct + e) * C_DIM + (c0 + 16 * j + lrow)] =
            acc[i][j][e];
}

// ---------------- K2a: reduce partials -> G ---------------------------------
__global__ __launch_bounds__(256) void k2a_reduce(const float* __restrict__ gpart,
                                                  float* __restrict__ G,
                                                  int nchunk) {
  const size_t total = (size_t)NB * C_DIM * C_DIM;
  size_t e0 = ((size_t)blockIdx.x * 256 + threadIdx.x) * 4;
  f32x4 s = {};
  for (int c = 0; c < nchunk; ++c) s += *(const f32x4*)(gpart + c * total + e0);
  *(f32x4*)(G + e0) = s;
}

// ---------------- K2b1: Tt[b] = [Wq|Wk]^T @ G  (384x192), uses G symmetry ---
__global__ __launch_bounds__(256) void k2b1_t(const float* __restrict__ G,
                                              const float* __restrict__ wqkv,
                                              float* __restrict__ Tt) {
  const int b = blockIdx.y, rb = blockIdx.x;  // rb 0..5 -> 64 rows
  const int lane = threadIdx.x & 63, wid = threadIdx.x >> 6;
  const int lrow = lane & 15, loct = lane >> 4;
  const float* Gb = G + (size_t)b * C_DIM * C_DIM;
  const int ddA = rb * 64 + wid * 16 + lrow;  // < 384, == wqkv column index
  f32x4 acc[12] = {};
  for (int s = 0; s < 6; ++s) {
    bf16x8 fa;
#pragma unroll
    for (int e = 0; e < 8; ++e)
      fa[e] = (__bf16)wqkv[(size_t)(32 * s + 8 * loct + e) * 576 + ddA];
#pragma unroll
    for (int j = 0; j < 12; ++j) {
      bf16x8 fb = cvt8(Gb + (size_t)(16 * j + lrow) * C_DIM + 32 * s + 8 * loct);
      acc[j] = mfma16(fa, fb, acc[j]);
    }
  }
  float* To = Tt + (size_t)b * 384 * C_DIM;
#pragma unroll
  for (int j = 0; j < 12; ++j)
#pragma unroll
    for (int e = 0; e < 4; ++e)
      To[(size_t)(rb * 64 + wid * 16 + 4 * loct + e) * C_DIM + 16 * j + lrow] =
          acc[j][e];
}

// ---------------- K2b2: per (b,h): S, norms, softmax, Yt -------------------
__global__ __launch_bounds__(256) void k2b2_attn(const float* __restrict__ Tt,
                                                 const float* __restrict__ wqkv,
                                                 const float* __restrict__ temp,
                                                 float* __restrict__ Yt) {
  const int b = blockIdx.y, h = blockIdx.x;
  __shared__ float SL[32][33];
  __shared__ float qn2L[HD], kn2L[HD];
  const int t = threadIdx.x;
  const int lane = t & 63, wid = t >> 6;
  const int lrow = lane & 15, loct = lane >> 4;
  const float* Tb = Tt + (size_t)b * 384 * C_DIM;
  const int r = wid >> 1, j = wid & 1;  // 2x2 tiles cover 32x32 (clip to 24x24)
  f32x4 acc = {};
  for (int s = 0; s < 6; ++s) {
    bf16x8 fa = cvt8(Tb + (size_t)(h * HD + 16 * r + lrow) * C_DIM + 32 * s + 8 * loct);
    bf16x8 fb;
#pragma unroll
    for (int e = 0; e < 8; ++e)
      fb[e] = (__bf16)wqkv[(size_t)(32 * s + 8 * loct + e) * 576 + 192 + h * HD +
                           16 * j + lrow];
    acc = mfma16(fa, fb, acc);
  }
#pragma unroll
  for (int e = 0; e < 4; ++e) {
    int d = 16 * r + 4 * loct + e, ee = 16 * j + lrow;
    if (d < HD && ee < HD) SL[d][ee] = acc[e];
  }
  if (t < 48) {  // squared norms: diag of Wq^T G Wq / Wk^T G Wk
    const int dd = (t < 24) ? t : t - 24;
    const int row = ((t < 24) ? 0 : 192) + h * HD + dd;
    float s = 0.f;
    for (int c = 0; c < C_DIM; ++c)
      s += Tb[(size_t)row * C_DIM + c] * wqkv[(size_t)c * 576 + row];
    if (t < 24) qn2L[dd] = s; else kn2L[dd] = s;
  }
  __syncthreads();
  if (t < HD) {  // softmax row t
    const float tp = temp[h];
    float nq = fmaxf(sqrtf(fmaxf(qn2L[t], 0.f)), EPSN);
    float lg[HD];
    float m = -1e30f;
#pragma unroll
    for (int e = 0; e < HD; ++e) {
      float nk = fmaxf(sqrtf(fmaxf(kn2L[e], 0.f)), EPSN);
      lg[e] = SL[t][e] / (nq * nk) * tp;
      m = fmaxf(m, lg[e]);
    }
    float sum = 0.f;
#pragma unroll
    for (int e = 0; e < HD; ++e) { lg[e] = __expf(lg[e] - m); sum += lg[e]; }
    float inv = 1.f / sum;
#pragma unroll
    for (int e = 0; e < HD; ++e) SL[t][e] = lg[e] * inv;
  }
  __syncthreads();
  if (t < C_DIM) {  // Yt[b][ci=t][h*24+d] = sum_e attn[d][e] * Wv[t][e]
    float wv[HD];
#pragma unroll
    for (int e = 0; e < HD; ++e)
      wv[e] = wqkv[(size_t)t * 576 + 384 + h * HD + e];
    float* Yo = Yt + ((size_t)b * C_DIM + t) * C_DIM + h * HD;
#pragma unroll
    for (int d = 0; d < HD; ++d) {
      float y = 0.f;
#pragma unroll
      for (int e = 0; e < HD; ++e) y += SL[d][e] * wv[e];
      Yo[d] = y;
    }
  }
}

// ---------------- K2c: M[b] = Wproj^T @ Y  (bf16 out) -----------------------
__global__ __launch_bounds__(256) void k2c_m(const float* __restrict__ wproj,
                                             const float* __restrict__ Yt,
                                             __bf16* __restrict__ M) {
  const int b = blockIdx.y, rb = blockIdx.x;  // rb 0..2 -> 64 rows
  const int lane = threadIdx.x & 63, wid = threadIdx.x >> 6;
  const int lrow = lane & 15, loct = lane >> 4;
  const float* Yb = Yt + (size_t)b * C_DIM * C_DIM;
  const int coA = rb * 64 + wid * 16 + lrow;
  f32x4 acc[12] = {};
  for (int s = 0; s < 6; ++s) {
    bf16x8 fa;
#pragma unroll
    for (int e = 0; e < 8; ++e)
      fa[e] = (__bf16)wproj[(size_t)(32 * s + 8 * loct + e) * C_DIM + coA];
#pragma unroll
    for (int j = 0; j < 12; ++j) {
      bf16x8 fb = cvt8(Yb + (size_t)(16 * j + lrow) * C_DIM + 32 * s + 8 * loct);
      acc[j] = mfma16(fa, fb, acc[j]);
    }
  }
  __bf16* Mo = M + (size_t)b * C_DIM * C_DIM;
#pragma unroll
  for (int j = 0; j < 12; ++j)
#pragma unroll
    for (int e = 0; e < 4; ++e)
      Mo[(size_t)(rb * 64 + wid * 16 + 4 * loct + e) * C_DIM + 16 * j + lrow] =
          (__bf16)acc[j][e];
}

// ---------------- K3 v6 (proven 95us): out[b] = M[b] @ x[b] + bias ----------
// Token-interleaved fragments; half-M in 36.8KB swizzled LDS; f32x4 x loads;
// per-wave LDS transpose epilogue -> dwordx4 store runs.
__global__ __launch_bounds__(256, 3) void k3_out(const float* __restrict__ x,
                                                 const __bf16* __restrict__ M,
                                                 const float* __restrict__ bproj,
                                                 float* __restrict__ out) {
  const int nt = blockIdx.x, half = blockIdx.y, b = blockIdx.z;
  const int rbase = half * 96;
  __shared__ __bf16 Ml[96 * C_DIM];  // 36864B; overlaid by epi after main loop
  __shared__ float biasL[96];
  const int t = threadIdx.x;
  const int lane = t & 63, w = t >> 6;
  const int lrow = lane & 15, loct = lane >> 4;

  const __bf16* Mb = M + (size_t)b * C_DIM * C_DIM + (size_t)rbase * C_DIM;
  for (int i = t; i < 96 * 24; i += 256) {
    int row = i / 24, ch = i % 24;
    bf16x8 v = *(const bf16x8*)(Mb + row * C_DIM + ch * 8);
    *(bf16x8*)(Ml + row * C_DIM + ((ch ^ (row & 7)) * 8)) = v;
  }
  if (t < 96) biasL[t] = bproj[rbase + t];
  __syncthreads();

  const float* xb = x + (size_t)b * C_DIM * NTOK;
  float* ob = out + (size_t)b * C_DIM * NTOK;
  const int n0 = nt * 256 + w * 64;  // wave's 64-token window

  f32x4 acc[6][4] = {};
  f32x4 xs4[8];  // prefetch: slab's 8 channels x 4 consecutive tokens
#pragma unroll
  for (int e = 0; e < 8; ++e)
    xs4[e] = *(const f32x4*)(xb + (size_t)(8 * loct + e) * NTOK + n0 + 4 * lrow);

  for (int s = 0; s < 6; ++s) {
    bf16x8 fb[4];  // fb[nf][e] = x[ch=32s+8loct+e][tok=n0+4*lrow+nf]
#pragma unroll
    for (int nf = 0; nf < 4; ++nf)
#pragma unroll
      for (int e = 0; e < 8; ++e)
        fb[nf][e] = (__bf16)xs4[e][nf];
    if (s < 5) {
#pragma unroll
      for (int e = 0; e < 8; ++e)
        xs4[e] = *(const f32x4*)(xb + (size_t)(32 * (s + 1) + 8 * loct + e) * NTOK +
                                 n0 + 4 * lrow);
    }
#pragma unroll
    for (int tt = 0; tt < 6; ++tt) {
      int rowb = 16 * tt + lrow;
      bf16x8 fa = *(const bf16x8*)(Ml + rowb * C_DIM +
                                   (((4 * s + loct) ^ (rowb & 7)) * 8));
#pragma unroll
      for (int nf = 0; nf < 4; ++nf)
        acc[tt][nf] = mfma16(fa, fb[nf], acc[tt][nf]);
    }
  }

  __syncthreads();  // all waves done reading Ml; safe to overlay epi
  // per-wave transpose buffer: 16 rows x 64 tokens, stride 68 f32
  float* epi_w = (float*)Ml + w * 1088;
#pragma unroll
  for (int tt = 0; tt < 6; ++tt) {
    f32x4 bias4 = *(const f32x4*)(biasL + 16 * tt + 4 * loct);  // rows 4loct+e
#pragma unroll
    for (int e = 0; e < 4; ++e) {
      f32x4 v;
      v[0] = acc[tt][0][e] + bias4[e];
      v[1] = acc[tt][1][e] + bias4[e];
      v[2] = acc[tt][2][e] + bias4[e];
      v[3] = acc[tt][3][e] + bias4[e];  // tokens 4*lrow+0..3 of row 16tt+4loct+e
      *(f32x4*)(epi_w + (4 * loct + e) * 68 + 4 * lrow) = v;
    }
    // wave-local ds_write -> ds_read ordered by program order, no barrier
#pragma unroll
    for (int h = 0; h < 4; ++h) {
      int r = 4 * h + loct;
      f32x4 v = *(const f32x4*)(epi_w + r * 68 + 4 * lrow);
      *(f32x4*)(ob + (size_t)(rbase + 16 * tt + r) * NTOK + n0 + 4 * lrow) = v;
    }
  }
}

extern "C" void kernel_launch(void* const* d_in, const int* in_sizes, int n_in,
                              void* d_out, int out_size, void* d_ws, size_t ws_size,
                              hipStream_t stream) {
  const float* x = (const float*)d_in[0];
  const float* wqkv = (const float*)d_in[1];
  const float* wproj = (const float*)d_in[2];
  const float* bproj = (const float*)d_in[3];
  const float* temp = (const float*)d_in[4];
  float* out = (float*)d_out;

  const size_t GSZ = (size_t)NB * C_DIM * C_DIM;  // 589824 floats
  const size_t TSZ = (size_t)NB * 384 * C_DIM;    // 1179648 floats
  int nchunk = 32;
  while (nchunk > 1 &&
         ((size_t)nchunk * GSZ + GSZ + TSZ + GSZ + GSZ) * 4 > ws_size)
    nchunk >>= 1;
  float* wsf = (float*)d_ws;
  float* gpart = wsf;
  float* G = gpart + (size_t)nchunk * GSZ;
  float* Tt = G + GSZ;
  float* Yt = Tt + TSZ;
  __bf16* M = (__bf16*)(Yt + GSZ);

  k1_gram<<<dim3(nchunk, NB), 256, 0, stream>>>(x, gpart, NTOK / nchunk);
  k2a_reduce<<<dim3(576), 256, 0, stream>>>(gpart, G, nchunk);
  k2b1_t<<<dim3(6, NB), 256, 0, stream>>>(G, wqkv, Tt);
  k2b2_attn<<<dim3(NH, NB), 256, 0, stream>>>(Tt, wqkv, temp, Yt);
  k2c_m<<<dim3(3, NB), 256, 0, stream>>>(wproj, Yt, M);
  k3_out<<<dim3(NTOK / 256, 2, NB), 256, 0, stream>>>(x, M, bproj, out);
}

// Round 14
// 222.835 us; speedup vs baseline: 1.7665x; 1.0444x over previous
//
#include <hip/hip_runtime.h>
#include <hip/hip_bf16.h>
#include <math.h>

#define C_DIM 192
#define NTOK 16384
#define NB 16
#define NH 8
#define HD 24
#define EPSN 1e-12f

typedef float f32x4 __attribute__((ext_vector_type(4)));
typedef __bf16 bf16x4 __attribute__((ext_vector_type(4)));
typedef __bf16 bf16x8 __attribute__((ext_vector_type(8)));

__device__ __forceinline__ f32x4 mfma16(bf16x8 a, bf16x8 b, f32x4 c) {
  return __builtin_amdgcn_mfma_f32_16x16x32_bf16(a, b, c, 0, 0, 0);
}

// load 8 consecutive f32 (16B-aligned x2) and convert to 8 bf16
__device__ __forceinline__ bf16x8 cvt8(const float* __restrict__ p) {
  f32x4 a = *(const f32x4*)p;
  f32x4 b = *(const f32x4*)(p + 4);
  bf16x8 r;
  r[0] = (__bf16)a[0]; r[1] = (__bf16)a[1]; r[2] = (__bf16)a[2]; r[3] = (__bf16)a[3];
  r[4] = (__bf16)b[0]; r[5] = (__bf16)b[1]; r[6] = (__bf16)b[2]; r[7] = (__bf16)b[3];
  return r;
}

// ---------------- K1: partial Gram, depth-2 staging (R10-proven) ------------
// bf16 gpart + symmetry skip: quadrant (96,0) [wid==2] is a bitwise transpose
// of (0,96) (MFMA symmetric pairs sum identical products in identical order),
// so it is never stored; k2a mirrors it. gpart traffic 75->28MB each way.
__global__ __launch_bounds__(256, 2) void k1_gram(const float* __restrict__ x,
                                                  __bf16* __restrict__ gpart,
                                                  int kc) {
  const int b = blockIdx.y, chunk = blockIdx.x;
  const float* xb = x + (size_t)b * C_DIM * NTOK + (size_t)chunk * kc;
  __shared__ __bf16 xsh[2][C_DIM * 40];  // 2 x 15KB, stride 40
  const int t = threadIdx.x;
  const int lane = t & 63, wid = t >> 6;
  const int lrow = lane & 15, loct = lane >> 4;
  const int r0 = (wid >> 1) * 96, c0 = (wid & 1) * 96;
  f32x4 acc[6][6] = {};
  f32x4 sA[6], sB[6];
  const int nst = kc >> 5;  // 16 at nchunk=32

#define K1_LOADR(dst, ks)                                                      \
  {                                                                            \
    _Pragma("unroll") for (int it = 0; it < 6; ++it) {                         \
      int idx = it * 256 + t, r = idx >> 3, c8 = idx & 7;                      \
      dst[it] = *(const f32x4*)(xb + (size_t)r * NTOK + (ks) + 4 * c8);        \
    }                                                                          \
  }
#define K1_STORE(buf, src)                                                     \
  {                                                                            \
    _Pragma("unroll") for (int it = 0; it < 6; ++it) {                         \
      int idx = it * 256 + t, r = idx >> 3, c8 = idx & 7;                      \
      bf16x4 w;                                                                \
      w[0] = (__bf16)src[it][0]; w[1] = (__bf16)src[it][1];                    \
      w[2] = (__bf16)src[it][2]; w[3] = (__bf16)src[it][3];                    \
      *(bf16x4*)(&xsh[buf][r * 40 + 4 * c8]) = w;                              \
    }                                                                          \
  }
#define K1_COMP(buf)                                                           \
  {                                                                            \
    bf16x8 fa[6];                                                              \
    _Pragma("unroll") for (int i = 0; i < 6; ++i)                              \
        fa[i] = *(const bf16x8*)(&xsh[buf][(r0 + 16 * i + lrow) * 40 +         \
                                           8 * loct]);                         \
    _Pragma("unroll") for (int j = 0; j < 6; ++j) {                            \
      bf16x8 fb =                                                              \
          *(const bf16x8*)(&xsh[buf][(c0 + 16 * j + lrow) * 40 + 8 * loct]);   \
      _Pragma("unroll") for (int i = 0; i < 6; ++i)                            \
          acc[i][j] = mfma16(fa[i], fb, acc[i][j]);                            \
    }                                                                          \
  }

  K1_LOADR(sA, 0);      // data(0)
  K1_STORE(0, sA);      // lds0 = data(0)
  K1_LOADR(sB, 32);     // data(1) in flight
  __syncthreads();

  for (int s = 0; s < nst; s += 2) {
    if (s + 2 < nst) K1_LOADR(sA, 32 * (s + 2));  // data(s+2) in flight
    K1_COMP(0);                                   // compute data(s)
    K1_STORE(1, sB);                              // lds1 = data(s+1)
    __syncthreads();
    if (s + 3 < nst) K1_LOADR(sB, 32 * (s + 3));  // data(s+3) in flight
    K1_COMP(1);                                   // compute data(s+1)
    if (s + 2 < nst) K1_STORE(0, sA);             // lds0 = data(s+2)
    __syncthreads();
  }
#undef K1_LOADR
#undef K1_STORE
#undef K1_COMP

  if (wid != 2) {  // (96,0) quadrant == transpose of (0,96): not stored
    __bf16* gp = gpart + ((size_t)chunk * NB + b) * C_DIM * C_DIM;
#pragma unroll
    for (int i = 0; i < 6; ++i)
#pragma unroll
      for (int j = 0; j < 6; ++j)
#pragma unroll
        for (int e = 0; e < 4; ++e)
          gp[(size_t)(r0 + 16 * i + 4 * loct + e) * C_DIM + (c0 + 16 * j + lrow)] =
              (__bf16)acc[i][j][e];
  }
}

// ---------------- K2a: reduce bf16 partials -> G (with (96,0) mirror) -------
// Quadrants qi: 0=(0,0), 1=(0,96) [also scatter-writes its transpose into
// (96,0)], 2=(96,96). 2304 threads/quadrant/batch; chunk-ordered f32 sums.
__global__ __launch_bounds__(256) void k2a_reduce(const __bf16* __restrict__ gpart,
                                                  float* __restrict__ G,
                                                  int nchunk) {
  const int qi = blockIdx.y, b = blockIdx.z;
  const int idx = blockIdx.x * 256 + threadIdx.x;  // < 2304
  const int r = idx / 24, c4 = idx % 24;
  const int r_off = (qi == 2) ? 96 : 0;
  const int c_off = (qi == 0) ? 0 : 96;
  const size_t total = (size_t)NB * C_DIM * C_DIM;
  const size_t base = (size_t)b * C_DIM * C_DIM +
                      (size_t)(r_off + r) * C_DIM + c_off + 4 * c4;
  float s0 = 0.f, s1 = 0.f, s2 = 0.f, s3 = 0.f;
  for (int ch = 0; ch < nchunk; ++ch) {
    bf16x4 v = *(const bf16x4*)(gpart + ch * total + base);
    s0 += (float)v[0]; s1 += (float)v[1]; s2 += (float)v[2]; s3 += (float)v[3];
  }
  float* Gb = G + (size_t)b * C_DIM * C_DIM;
  f32x4 sv; sv[0] = s0; sv[1] = s1; sv[2] = s2; sv[3] = s3;
  *(f32x4*)(Gb + (size_t)(r_off + r) * C_DIM + c_off + 4 * c4) = sv;
  if (qi == 1) {  // mirror (0,96) -> (96,0)
    Gb[(size_t)(96 + 4 * c4 + 0) * C_DIM + r] = s0;
    Gb[(size_t)(96 + 4 * c4 + 1) * C_DIM + r] = s1;
    Gb[(size_t)(96 + 4 * c4 + 2) * C_DIM + r] = s2;
    Gb[(size_t)(96 + 4 * c4 + 3) * C_DIM + r] = s3;
  }
}

// ---------------- K2b1: Tt[b] = [Wq|Wk]^T @ G  (384x192), uses G symmetry ---
__global__ __launch_bounds__(256) void k2b1_t(const float* __restrict__ G,
                                              const float* __restrict__ wqkv,
                                              float* __restrict__ Tt) {
  const int b = blockIdx.y, rb = blockIdx.x;  // rb 0..5 -> 64 rows
  const int lane = threadIdx.x & 63, wid = threadIdx.x >> 6;
  const int lrow = lane & 15, loct = lane >> 4;
  const float* Gb = G + (size_t)b * C_DIM * C_DIM;
  const int ddA = rb * 64 + wid * 16 + lrow;  // < 384, == wqkv column index
  f32x4 acc[12] = {};
  for (int s = 0; s < 6; ++s) {
    bf16x8 fa;
#pragma unroll
    for (int e = 0; e < 8; ++e)
      fa[e] = (__bf16)wqkv[(size_t)(32 * s + 8 * loct + e) * 576 + ddA];
#pragma unroll
    for (int j = 0; j < 12; ++j) {
      bf16x8 fb = cvt8(Gb + (size_t)(16 * j + lrow) * C_DIM + 32 * s + 8 * loct);
      acc[j] = mfma16(fa, fb, acc[j]);
    }
  }
  float* To = Tt + (size_t)b * 384 * C_DIM;
#pragma unroll
  for (int j = 0; j < 12; ++j)
#pragma unroll
    for (int e = 0; e < 4; ++e)
      To[(size_t)(rb * 64 + wid * 16 + 4 * loct + e) * C_DIM + 16 * j + lrow] =
          acc[j][e];
}

// ---------------- K2b2: per (b,h): S, norms, softmax, Yt -------------------
__global__ __launch_bounds__(256) void k2b2_attn(const float* __restrict__ Tt,
                                                 const float* __restrict__ wqkv,
                                                 const float* __restrict__ temp,
                                                 float* __restrict__ Yt) {
  const int b = blockIdx.y, h = blockIdx.x;
  __shared__ float SL[32][33];
  __shared__ float qn2L[HD], kn2L[HD];
  const int t = threadIdx.x;
  const int lane = t & 63, wid = t >> 6;
  const int lrow = lane & 15, loct = lane >> 4;
  const float* Tb = Tt + (size_t)b * 384 * C_DIM;
  const int r = wid >> 1, j = wid & 1;  // 2x2 tiles cover 32x32 (clip to 24x24)
  f32x4 acc = {};
  for (int s = 0; s < 6; ++s) {
    bf16x8 fa = cvt8(Tb + (size_t)(h * HD + 16 * r + lrow) * C_DIM + 32 * s + 8 * loct);
    bf16x8 fb;
#pragma unroll
    for (int e = 0; e < 8; ++e)
      fb[e] = (__bf16)wqkv[(size_t)(32 * s + 8 * loct + e) * 576 + 192 + h * HD +
                           16 * j + lrow];
    acc = mfma16(fa, fb, acc);
  }
#pragma unroll
  for (int e = 0; e < 4; ++e) {
    int d = 16 * r + 4 * loct + e, ee = 16 * j + lrow;
    if (d < HD && ee < HD) SL[d][ee] = acc[e];
  }
  if (t < 48) {  // squared norms: diag of Wq^T G Wq / Wk^T G Wk
    const int dd = (t < 24) ? t : t - 24;
    const int row = ((t < 24) ? 0 : 192) + h * HD + dd;
    float s = 0.f;
    for (int c = 0; c < C_DIM; ++c)
      s += Tb[(size_t)row * C_DIM + c] * wqkv[(size_t)c * 576 + row];
    if (t < 24) qn2L[dd] = s; else kn2L[dd] = s;
  }
  __syncthreads();
  if (t < HD) {  // softmax row t
    const float tp = temp[h];
    float nq = fmaxf(sqrtf(fmaxf(qn2L[t], 0.f)), EPSN);
    float lg[HD];
    float m = -1e30f;
#pragma unroll
    for (int e = 0; e < HD; ++e) {
      float nk = fmaxf(sqrtf(fmaxf(kn2L[e], 0.f)), EPSN);
      lg[e] = SL[t][e] / (nq * nk) * tp;
      m = fmaxf(m, lg[e]);
    }
    float sum = 0.f;
#pragma unroll
    for (int e = 0; e < HD; ++e) { lg[e] = __expf(lg[e] - m); sum += lg[e]; }
    float inv = 1.f / sum;
#pragma unroll
    for (int e = 0; e < HD; ++e) SL[t][e] = lg[e] * inv;
  }
  __syncthreads();
  if (t < C_DIM) {  // Yt[b][ci=t][h*24+d] = sum_e attn[d][e] * Wv[t][e]
    float wv[HD];
#pragma unroll
    for (int e = 0; e < HD; ++e)
      wv[e] = wqkv[(size_t)t * 576 + 384 + h * HD + e];
    float* Yo = Yt + ((size_t)b * C_DIM + t) * C_DIM + h * HD;
#pragma unroll
    for (int d = 0; d < HD; ++d) {
      float y = 0.f;
#pragma unroll
      for (int e = 0; e < HD; ++e) y += SL[d][e] * wv[e];
      Yo[d] = y;
    }
  }
}

// ---------------- K2c: M[b] = Wproj^T @ Y  (bf16 out) -----------------------
__global__ __launch_bounds__(256) void k2c_m(const float* __restrict__ wproj,
                                             const float* __restrict__ Yt,
                                             __bf16* __restrict__ M) {
  const int b = blockIdx.y, rb = blockIdx.x;  // rb 0..2 -> 64 rows
  const int lane = threadIdx.x & 63, wid = threadIdx.x >> 6;
  const int lrow = lane & 15, loct = lane >> 4;
  const float* Yb = Yt + (size_t)b * C_DIM * C_DIM;
  const int coA = rb * 64 + wid * 16 + lrow;
  f32x4 acc[12] = {};
  for (int s = 0; s < 6; ++s) {
    bf16x8 fa;
#pragma unroll
    for (int e = 0; e < 8; ++e)
      fa[e] = (__bf16)wproj[(size_t)(32 * s + 8 * loct + e) * C_DIM + coA];
#pragma unroll
    for (int j = 0; j < 12; ++j) {
      bf16x8 fb = cvt8(Yb + (size_t)(16 * j + lrow) * C_DIM + 32 * s + 8 * loct);
      acc[j] = mfma16(fa, fb, acc[j]);
    }
  }
  __bf16* Mo = M + (size_t)b * C_DIM * C_DIM;
#pragma unroll
  for (int j = 0; j < 12; ++j)
#pragma unroll
    for (int e = 0; e < 4; ++e)
      Mo[(size_t)(rb * 64 + wid * 16 + 4 * loct + e) * C_DIM + 16 * j + lrow] =
          (__bf16)acc[j][e];
}

// ---------------- K3 v6 (proven 95us): out[b] = M[b] @ x[b] + bias ----------
// Token-interleaved fragments; half-M in 36.8KB swizzled LDS; f32x4 x loads;
// per-wave LDS transpose epilogue -> dwordx4 store runs.
__global__ __launch_bounds__(256, 3) void k3_out(const float* __restrict__ x,
                                                 const __bf16* __restrict__ M,
                                                 const float* __restrict__ bproj,
                                                 float* __restrict__ out) {
  const int nt = blockIdx.x, half = blockIdx.y, b = blockIdx.z;
  const int rbase = half * 96;
  __shared__ __bf16 Ml[96 * C_DIM];  // 36864B; overlaid by epi after main loop
  __shared__ float biasL[96];
  const int t = threadIdx.x;
  const int lane = t & 63, w = t >> 6;
  const int lrow = lane & 15, loct = lane >> 4;

  const __bf16* Mb = M + (size_t)b * C_DIM * C_DIM + (size_t)rbase * C_DIM;
  for (int i = t; i < 96 * 24; i += 256) {
    int row = i / 24, ch = i % 24;
    bf16x8 v = *(const bf16x8*)(Mb + row * C_DIM + ch * 8);
    *(bf16x8*)(Ml + row * C_DIM + ((ch ^ (row & 7)) * 8)) = v;
  }
  if (t < 96) biasL[t] = bproj[rbase + t];
  __syncthreads();

  const float* xb = x + (size_t)b * C_DIM * NTOK;
  float* ob = out + (size_t)b * C_DIM * NTOK;
  const int n0 = nt * 256 + w * 64;  // wave's 64-token window

  f32x4 acc[6][4] = {};
  f32x4 xs4[8];  // prefetch: slab's 8 channels x 4 consecutive tokens
#pragma unroll
  for (int e = 0; e < 8; ++e)
    xs4[e] = *(const f32x4*)(xb + (size_t)(8 * loct + e) * NTOK + n0 + 4 * lrow);

  for (int s = 0; s < 6; ++s) {
    bf16x8 fb[4];  // fb[nf][e] = x[ch=32s+8loct+e][tok=n0+4*lrow+nf]
#pragma unroll
    for (int nf = 0; nf < 4; ++nf)
#pragma unroll
      for (int e = 0; e < 8; ++e)
        fb[nf][e] = (__bf16)xs4[e][nf];
    if (s < 5) {
#pragma unroll
      for (int e = 0; e < 8; ++e)
        xs4[e] = *(const f32x4*)(xb + (size_t)(32 * (s + 1) + 8 * loct + e) * NTOK +
                                 n0 + 4 * lrow);
    }
#pragma unroll
    for (int tt = 0; tt < 6; ++tt) {
      int rowb = 16 * tt + lrow;
      bf16x8 fa = *(const bf16x8*)(Ml + rowb * C_DIM +
                                   (((4 * s + loct) ^ (rowb & 7)) * 8));
#pragma unroll
      for (int nf = 0; nf < 4; ++nf)
        acc[tt][nf] = mfma16(fa, fb[nf], acc[tt][nf]);
    }
  }

  __syncthreads();  // all waves done reading Ml; safe to overlay epi
  // per-wave transpose buffer: 16 rows x 64 tokens, stride 68 f32
  float* epi_w = (float*)Ml + w * 1088;
#pragma unroll
  for (int tt = 0; tt < 6; ++tt) {
    f32x4 bias4 = *(const f32x4*)(biasL + 16 * tt + 4 * loct);  // rows 4loct+e
#pragma unroll
    for (int e = 0; e < 4; ++e) {
      f32x4 v;
      v[0] = acc[tt][0][e] + bias4[e];
      v[1] = acc[tt][1][e] + bias4[e];
      v[2] = acc[tt][2][e] + bias4[e];
      v[3] = acc[tt][3][e] + bias4[e];  // tokens 4*lrow+0..3 of row 16tt+4loct+e
      *(f32x4*)(epi_w + (4 * loct + e) * 68 + 4 * lrow) = v;
    }
    // wave-local ds_write -> ds_read ordered by program order, no barrier
#pragma unroll
    for (int h = 0; h < 4; ++h) {
      int r = 4 * h + loct;
      f32x4 v = *(const f32x4*)(epi_w + r * 68 + 4 * lrow);
      *(f32x4*)(ob + (size_t)(rbase + 16 * tt + r) * NTOK + n0 + 4 * lrow) = v;
    }
  }
}

extern "C" void kernel_launch(void* const* d_in, const int* in_sizes, int n_in,
                              void* d_out, int out_size, void* d_ws, size_t ws_size,
                              hipStream_t stream) {
  const float* x = (const float*)d_in[0];
  const float* wqkv = (const float*)d_in[1];
  const float* wproj = (const float*)d_in[2];
  const float* bproj = (const float*)d_in[3];
  const float* temp = (const float*)d_in[4];
  float* out = (float*)d_out;

  const size_t GSZ = (size_t)NB * C_DIM * C_DIM;  // 589824 elems
  const size_t TSZ = (size_t)NB * 384 * C_DIM;    // 1179648 floats
  int nchunk = 32;
  while (nchunk > 1 &&
         (size_t)nchunk * GSZ * 2 + (GSZ + TSZ + GSZ) * 4 + GSZ * 2 > ws_size)
    nchunk >>= 1;
  __bf16* gpart = (__bf16*)d_ws;
  float* G = (float*)(gpart + (size_t)nchunk * GSZ);
  float* Tt = G + GSZ;
  float* Yt = Tt + TSZ;
  __bf16* M = (__bf16*)(Yt + GSZ);

  k1_gram<<<dim3(nchunk, NB), 256, 0, stream>>>(x, gpart, NTOK / nchunk);
  k2a_reduce<<<dim3(9, 3, NB), 256, 0, stream>>>(gpart, G, nchunk);
  k2b1_t<<<dim3(6, NB), 256, 0, stream>>>(G, wqkv, Tt);
  k2b2_attn<<<dim3(NH, NB), 256, 0, stream>>>(Tt, wqkv, temp, Yt);
  k2c_m<<<dim3(3, NB), 256, 0, stream>>>(wproj, Yt, M);
  k3_out<<<dim3(NTOK / 256, 2, NB), 256, 0, stream>>>(x, M, bproj, out);
}

// Round 15
// 208.307 us; speedup vs baseline: 1.8897x; 1.0697x over previous
//
#include <hip/hip_runtime.h>
#include <hip/hip_bf16.h>
#include <math.h>

#define C_DIM 192
#define NTOK 16384
#define NB 16
#define NH 8
#define HD 24
#define EPSN 1e-12f

typedef float f32x4 __attribute__((ext_vector_type(4)));
typedef __bf16 bf16x4 __attribute__((ext_vector_type(4)));
typedef __bf16 bf16x8 __attribute__((ext_vector_type(8)));

__device__ __forceinline__ f32x4 mfma16(bf16x8 a, bf16x8 b, f32x4 c) {
  return __builtin_amdgcn_mfma_f32_16x16x32_bf16(a, b, c, 0, 0, 0);
}

// load 8 consecutive f32 (16B-aligned x2) and convert to 8 bf16
__device__ __forceinline__ bf16x8 cvt8(const float* __restrict__ p) {
  f32x4 a = *(const f32x4*)p;
  f32x4 b = *(const f32x4*)(p + 4);
  bf16x8 r;
  r[0] = (__bf16)a[0]; r[1] = (__bf16)a[1]; r[2] = (__bf16)a[2]; r[3] = (__bf16)a[3];
  r[4] = (__bf16)b[0]; r[5] = (__bf16)b[1]; r[6] = (__bf16)b[2]; r[7] = (__bf16)b[3];
  return r;
}

// ---------------- K1: partial Gram, depth-2 staging (R10-proven) ------------
// bf16 gpart + symmetry skip (R14-proven).
__global__ __launch_bounds__(256, 2) void k1_gram(const float* __restrict__ x,
                                                  __bf16* __restrict__ gpart,
                                                  int kc) {
  const int b = blockIdx.y, chunk = blockIdx.x;
  const float* xb = x + (size_t)b * C_DIM * NTOK + (size_t)chunk * kc;
  __shared__ __bf16 xsh[2][C_DIM * 40];  // 2 x 15KB, stride 40
  const int t = threadIdx.x;
  const int lane = t & 63, wid = t >> 6;
  const int lrow = lane & 15, loct = lane >> 4;
  const int r0 = (wid >> 1) * 96, c0 = (wid & 1) * 96;
  f32x4 acc[6][6] = {};
  f32x4 sA[6], sB[6];
  const int nst = kc >> 5;  // 16 at nchunk=32

#define K1_LOADR(dst, ks)                                                      \
  {                                                                            \
    _Pragma("unroll") for (int it = 0; it < 6; ++it) {                         \
      int idx = it * 256 + t, r = idx >> 3, c8 = idx & 7;                      \
      dst[it] = *(const f32x4*)(xb + (size_t)r * NTOK + (ks) + 4 * c8);        \
    }                                                                          \
  }
#define K1_STORE(buf, src)                                                     \
  {                                                                            \
    _Pragma("unroll") for (int it = 0; it < 6; ++it) {                         \
      int idx = it * 256 + t, r = idx >> 3, c8 = idx & 7;                      \
      bf16x4 w;                                                                \
      w[0] = (__bf16)src[it][0]; w[1] = (__bf16)src[it][1];                    \
      w[2] = (__bf16)src[it][2]; w[3] = (__bf16)src[it][3];                    \
      *(bf16x4*)(&xsh[buf][r * 40 + 4 * c8]) = w;                              \
    }                                                                          \
  }
#define K1_COMP(buf)                                                           \
  {                                                                            \
    bf16x8 fa[6];                                                              \
    _Pragma("unroll") for (int i = 0; i < 6; ++i)                              \
        fa[i] = *(const bf16x8*)(&xsh[buf][(r0 + 16 * i + lrow) * 40 +         \
                                           8 * loct]);                         \
    _Pragma("unroll") for (int j = 0; j < 6; ++j) {                            \
      bf16x8 fb =                                                              \
          *(const bf16x8*)(&xsh[buf][(c0 + 16 * j + lrow) * 40 + 8 * loct]);   \
      _Pragma("unroll") for (int i = 0; i < 6; ++i)                            \
          acc[i][j] = mfma16(fa[i], fb, acc[i][j]);                            \
    }                                                                          \
  }

  K1_LOADR(sA, 0);      // data(0)
  K1_STORE(0, sA);      // lds0 = data(0)
  K1_LOADR(sB, 32);     // data(1) in flight
  __syncthreads();

  for (int s = 0; s < nst; s += 2) {
    if (s + 2 < nst) K1_LOADR(sA, 32 * (s + 2));  // data(s+2) in flight
    K1_COMP(0);                                   // compute data(s)
    K1_STORE(1, sB);                              // lds1 = data(s+1)
    __syncthreads();
    if (s + 3 < nst) K1_LOADR(sB, 32 * (s + 3));  // data(s+3) in flight
    K1_COMP(1);                                   // compute data(s+1)
    if (s + 2 < nst) K1_STORE(0, sA);             // lds0 = data(s+2)
    __syncthreads();
  }
#undef K1_LOADR
#undef K1_STORE
#undef K1_COMP

  if (wid != 2) {  // (96,0) quadrant == transpose of (0,96): not stored
    __bf16* gp = gpart + ((size_t)chunk * NB + b) * C_DIM * C_DIM;
#pragma unroll
    for (int i = 0; i < 6; ++i)
#pragma unroll
      for (int j = 0; j < 6; ++j)
#pragma unroll
        for (int e = 0; e < 4; ++e)
          gp[(size_t)(r0 + 16 * i + 4 * loct + e) * C_DIM + (c0 + 16 * j + lrow)] =
              (__bf16)acc[i][j][e];
  }
}

// ---------------- K2a: reduce bf16 partials -> G (with (96,0) mirror) -------
__global__ __launch_bounds__(256) void k2a_reduce(const __bf16* __restrict__ gpart,
                                                  float* __restrict__ G,
                                                  int nchunk) {
  const int qi = blockIdx.y, b = blockIdx.z;
  const int idx = blockIdx.x * 256 + threadIdx.x;  // < 2304
  const int r = idx / 24, c4 = idx % 24;
  const int r_off = (qi == 2) ? 96 : 0;
  const int c_off = (qi == 0) ? 0 : 96;
  const size_t total = (size_t)NB * C_DIM * C_DIM;
  const size_t base = (size_t)b * C_DIM * C_DIM +
                      (size_t)(r_off + r) * C_DIM + c_off + 4 * c4;
  float s0 = 0.f, s1 = 0.f, s2 = 0.f, s3 = 0.f;
  for (int ch = 0; ch < nchunk; ++ch) {
    bf16x4 v = *(const bf16x4*)(gpart + ch * total + base);
    s0 += (float)v[0]; s1 += (float)v[1]; s2 += (float)v[2]; s3 += (float)v[3];
  }
  float* Gb = G + (size_t)b * C_DIM * C_DIM;
  f32x4 sv; sv[0] = s0; sv[1] = s1; sv[2] = s2; sv[3] = s3;
  *(f32x4*)(Gb + (size_t)(r_off + r) * C_DIM + c_off + 4 * c4) = sv;
  if (qi == 1) {  // mirror (0,96) -> (96,0)
    Gb[(size_t)(96 + 4 * c4 + 0) * C_DIM + r] = s0;
    Gb[(size_t)(96 + 4 * c4 + 1) * C_DIM + r] = s1;
    Gb[(size_t)(96 + 4 * c4 + 2) * C_DIM + r] = s2;
    Gb[(size_t)(96 + 4 * c4 + 3) * C_DIM + r] = s3;
  }
}

// ---------------- K2b fused: per (b,h) T-rows -> S -> softmax -> Yt ---------
// Phase 1 (waves 0-2): 48 packed rows {24 q, 24 k} of [Wq|Wk]^T @ G via the
// k2b1-proven MFMA mapping, per-lane wqkv column = packed row id; stored to
// LDS Tl[48][196] (stride 196 avoids the stride-192 4-way write conflict).
// Phase 2: original k2b2 S/norms/softmax/Yt with Tt-global reads -> Tl reads.
// Eliminates the Tt global round-trip (9.4MB) and one kernel launch.
__global__ __launch_bounds__(256) void k2b_fused(const float* __restrict__ G,
                                                 const float* __restrict__ wqkv,
                                                 const float* __restrict__ temp,
                                                 float* __restrict__ Yt) {
  const int h = blockIdx.x, b = blockIdx.y;
  __shared__ float Tl[48 * 196];  // 37.6KB
  __shared__ float SL[32][33];
  __shared__ float qn2L[HD], kn2L[HD];
  const int t = threadIdx.x;
  const int lane = t & 63, wid = t >> 6;
  const int lrow = lane & 15, loct = lane >> 4;
  const float* Gb = G + (size_t)b * C_DIM * C_DIM;

  // ---- Phase 1: Tl[p][:] = wqkv[:, col(p)]^T @ G, p = wid*16 + lrow ----
  if (wid < 3) {
    const int p = wid * 16 + lrow;  // packed row 0..47
    const int col = (p < HD) ? (h * HD + p) : (192 + h * HD + p - HD);
    f32x4 acc[12] = {};
    for (int s = 0; s < 6; ++s) {
      bf16x8 fa;
#pragma unroll
      for (int e = 0; e < 8; ++e)
        fa[e] = (__bf16)wqkv[(size_t)(32 * s + 8 * loct + e) * 576 + col];
#pragma unroll
      for (int j = 0; j < 12; ++j) {
        bf16x8 fb = cvt8(Gb + (size_t)(16 * j + lrow) * C_DIM + 32 * s + 8 * loct);
        acc[j] = mfma16(fa, fb, acc[j]);
      }
    }
#pragma unroll
    for (int j = 0; j < 12; ++j)
#pragma unroll
      for (int e = 0; e < 4; ++e)
        Tl[(wid * 16 + 4 * loct + e) * 196 + 16 * j + lrow] = acc[j][e];
  }
  __syncthreads();

  // ---- Phase 2: S = Tq . Wk_h (packed rows 0..23 are q-rows) ----
  const int r = wid >> 1, j = wid & 1;  // 2x2 tiles cover 32x32 (clip 24x24)
  f32x4 acc = {};
  for (int s = 0; s < 6; ++s) {
    // packed rows 16r+lrow in [0,32): >=24 hits k-rows, discarded below
    bf16x8 fa = cvt8(&Tl[(16 * r + lrow) * 196 + 32 * s + 8 * loct]);
    bf16x8 fb;
#pragma unroll
    for (int e = 0; e < 8; ++e)
      fb[e] = (__bf16)wqkv[(size_t)(32 * s + 8 * loct + e) * 576 + 192 + h * HD +
                           16 * j + lrow];
    acc = mfma16(fa, fb, acc);
  }
#pragma unroll
  for (int e = 0; e < 4; ++e) {
    int d = 16 * r + 4 * loct + e, ee = 16 * j + lrow;
    if (d < HD && ee < HD) SL[d][ee] = acc[e];
  }
  if (t < 48) {  // squared norms: diag of Wq^T G Wq / Wk^T G Wk
    const int dd = (t < HD) ? t : t - HD;
    const int row = ((t < HD) ? 0 : 192) + h * HD + dd;  // wqkv column
    float s = 0.f;
    for (int c = 0; c < C_DIM; ++c)
      s += Tl[t * 196 + c] * wqkv[(size_t)c * 576 + row];
    if (t < HD) qn2L[dd] = s; else kn2L[dd] = s;
  }
  __syncthreads();
  if (t < HD) {  // softmax row t
    const float tp = temp[h];
    float nq = fmaxf(sqrtf(fmaxf(qn2L[t], 0.f)), EPSN);
    float lg[HD];
    float m = -1e30f;
#pragma unroll
    for (int e = 0; e < HD; ++e) {
      float nk = fmaxf(sqrtf(fmaxf(kn2L[e], 0.f)), EPSN);
      lg[e] = SL[t][e] / (nq * nk) * tp;
      m = fmaxf(m, lg[e]);
    }
    float sum = 0.f;
#pragma unroll
    for (int e = 0; e < HD; ++e) { lg[e] = __expf(lg[e] - m); sum += lg[e]; }
    float inv = 1.f / sum;
#pragma unroll
    for (int e = 0; e < HD; ++e) SL[t][e] = lg[e] * inv;
  }
  __syncthreads();
  if (t < C_DIM) {  // Yt[b][ci=t][h*24+d] = sum_e attn[d][e] * Wv[t][e]
    float wv[HD];
#pragma unroll
    for (int e = 0; e < HD; ++e)
      wv[e] = wqkv[(size_t)t * 576 + 384 + h * HD + e];
    float* Yo = Yt + ((size_t)b * C_DIM + t) * C_DIM + h * HD;
#pragma unroll
    for (int d = 0; d < HD; ++d) {
      float y = 0.f;
#pragma unroll
      for (int e = 0; e < HD; ++e) y += SL[d][e] * wv[e];
      Yo[d] = y;
    }
  }
}

// ---------------- K2c: M[b] = Wproj^T @ Y  (bf16 out) -----------------------
__global__ __launch_bounds__(256) void k2c_m(const float* __restrict__ wproj,
                                             const float* __restrict__ Yt,
                                             __bf16* __restrict__ M) {
  const int b = blockIdx.y, rb = blockIdx.x;  // rb 0..2 -> 64 rows
  const int lane = threadIdx.x & 63, wid = threadIdx.x >> 6;
  const int lrow = lane & 15, loct = lane >> 4;
  const float* Yb = Yt + (size_t)b * C_DIM * C_DIM;
  const int coA = rb * 64 + wid * 16 + lrow;
  f32x4 acc[12] = {};
  for (int s = 0; s < 6; ++s) {
    bf16x8 fa;
#pragma unroll
    for (int e = 0; e < 8; ++e)
      fa[e] = (__bf16)wproj[(size_t)(32 * s + 8 * loct + e) * C_DIM + coA];
#pragma unroll
    for (int j = 0; j < 12; ++j) {
      bf16x8 fb = cvt8(Yb + (size_t)(16 * j + lrow) * C_DIM + 32 * s + 8 * loct);
      acc[j] = mfma16(fa, fb, acc[j]);
    }
  }
  __bf16* Mo = M + (size_t)b * C_DIM * C_DIM;
#pragma unroll
  for (int j = 0; j < 12; ++j)
#pragma unroll
    for (int e = 0; e < 4; ++e)
      Mo[(size_t)(rb * 64 + wid * 16 + 4 * loct + e) * C_DIM + 16 * j + lrow] =
          (__bf16)acc[j][e];
}

// ---------------- K3 v6 (proven 95us): out[b] = M[b] @ x[b] + bias ----------
__global__ __launch_bounds__(256, 3) void k3_out(const float* __restrict__ x,
                                                 const __bf16* __restrict__ M,
                                                 const float* __restrict__ bproj,
                                                 float* __restrict__ out) {
  const int nt = blockIdx.x, half = blockIdx.y, b = blockIdx.z;
  const int rbase = half * 96;
  __shared__ __bf16 Ml[96 * C_DIM];  // 36864B; overlaid by epi after main loop
  __shared__ float biasL[96];
  const int t = threadIdx.x;
  const int lane = t & 63, w = t >> 6;
  const int lrow = lane & 15, loct = lane >> 4;

  const __bf16* Mb = M + (size_t)b * C_DIM * C_DIM + (size_t)rbase * C_DIM;
  for (int i = t; i < 96 * 24; i += 256) {
    int row = i / 24, ch = i % 24;
    bf16x8 v = *(const bf16x8*)(Mb + row * C_DIM + ch * 8);
    *(bf16x8*)(Ml + row * C_DIM + ((ch ^ (row & 7)) * 8)) = v;
  }
  if (t < 96) biasL[t] = bproj[rbase + t];
  __syncthreads();

  const float* xb = x + (size_t)b * C_DIM * NTOK;
  float* ob = out + (size_t)b * C_DIM * NTOK;
  const int n0 = nt * 256 + w * 64;  // wave's 64-token window

  f32x4 acc[6][4] = {};
  f32x4 xs4[8];  // prefetch: slab's 8 channels x 4 consecutive tokens
#pragma unroll
  for (int e = 0; e < 8; ++e)
    xs4[e] = *(const f32x4*)(xb + (size_t)(8 * loct + e) * NTOK + n0 + 4 * lrow);

  for (int s = 0; s < 6; ++s) {
    bf16x8 fb[4];  // fb[nf][e] = x[ch=32s+8loct+e][tok=n0+4*lrow+nf]
#pragma unroll
    for (int nf = 0; nf < 4; ++nf)
#pragma unroll
      for (int e = 0; e < 8; ++e)
        fb[nf][e] = (__bf16)xs4[e][nf];
    if (s < 5) {
#pragma unroll
      for (int e = 0; e < 8; ++e)
        xs4[e] = *(const f32x4*)(xb + (size_t)(32 * (s + 1) + 8 * loct + e) * NTOK +
                                 n0 + 4 * lrow);
    }
#pragma unroll
    for (int tt = 0; tt < 6; ++tt) {
      int rowb = 16 * tt + lrow;
      bf16x8 fa = *(const bf16x8*)(Ml + rowb * C_DIM +
                                   (((4 * s + loct) ^ (rowb & 7)) * 8));
#pragma unroll
      for (int nf = 0; nf < 4; ++nf)
        acc[tt][nf] = mfma16(fa, fb[nf], acc[tt][nf]);
    }
  }

  __syncthreads();  // all waves done reading Ml; safe to overlay epi
  // per-wave transpose buffer: 16 rows x 64 tokens, stride 68 f32
  float* epi_w = (float*)Ml + w * 1088;
#pragma unroll
  for (int tt = 0; tt < 6; ++tt) {
    f32x4 bias4 = *(const f32x4*)(biasL + 16 * tt + 4 * loct);  // rows 4loct+e
#pragma unroll
    for (int e = 0; e < 4; ++e) {
      f32x4 v;
      v[0] = acc[tt][0][e] + bias4[e];
      v[1] = acc[tt][1][e] + bias4[e];
      v[2] = acc[tt][2][e] + bias4[e];
      v[3] = acc[tt][3][e] + bias4[e];  // tokens 4*lrow+0..3 of row 16tt+4loct+e
      *(f32x4*)(epi_w + (4 * loct + e) * 68 + 4 * lrow) = v;
    }
    // wave-local ds_write -> ds_read ordered by program order, no barrier
#pragma unroll
    for (int h = 0; h < 4; ++h) {
      int r = 4 * h + loct;
      f32x4 v = *(const f32x4*)(epi_w + r * 68 + 4 * lrow);
      *(f32x4*)(ob + (size_t)(rbase + 16 * tt + r) * NTOK + n0 + 4 * lrow) = v;
    }
  }
}

extern "C" void kernel_launch(void* const* d_in, const int* in_sizes, int n_in,
                              void* d_out, int out_size, void* d_ws, size_t ws_size,
                              hipStream_t stream) {
  const float* x = (const float*)d_in[0];
  const float* wqkv = (const float*)d_in[1];
  const float* wproj = (const float*)d_in[2];
  const float* bproj = (const float*)d_in[3];
  const float* temp = (const float*)d_in[4];
  float* out = (float*)d_out;

  const size_t GSZ = (size_t)NB * C_DIM * C_DIM;  // 589824 elems
  int nchunk = 32;
  while (nchunk > 1 &&
         (size_t)nchunk * GSZ * 2 + GSZ * 4 + GSZ * 4 + GSZ * 2 > ws_size)
    nchunk >>= 1;
  __bf16* gpart = (__bf16*)d_ws;
  float* G = (float*)(gpart + (size_t)nchunk * GSZ);
  float* Yt = G + GSZ;
  __bf16* M = (__bf16*)(Yt + GSZ);

  k1_gram<<<dim3(nchunk, NB), 256, 0, stream>>>(x, gpart, NTOK / nchunk);
  k2a_reduce<<<dim3(9, 3, NB), 256, 0, stream>>>(gpart, G, nchunk);
  k2b_fused<<<dim3(NH, NB), 256, 0, stream>>>(G, wqkv, temp, Yt);
  k2c_m<<<dim3(3, NB), 256, 0, stream>>>(wproj, Yt, M);
  k3_out<<<dim3(NTOK / 256, 2, NB), 256, 0, stream>>>(x, M, bproj, out);
}

// Round 17
// 206.320 us; speedup vs baseline: 1.9079x; 1.0096x over previous
//
#include <hip/hip_runtime.h>
#include <hip/hip_bf16.h>
#include <math.h>

#define C_DIM 192
#define NTOK 16384
#define NB 16
#define NH 8
#define HD 24
#define EPSN 1e-12f

typedef float f32x4 __attribute__((ext_vector_type(4)));
typedef __bf16 bf16x4 __attribute__((ext_vector_type(4)));
typedef __bf16 bf16x8 __attribute__((ext_vector_type(8)));

__device__ __forceinline__ f32x4 mfma16(bf16x8 a, bf16x8 b, f32x4 c) {
  return __builtin_amdgcn_mfma_f32_16x16x32_bf16(a, b, c, 0, 0, 0);
}

__device__ __forceinline__ bf16x8 cvt8_2(f32x4 a, f32x4 b) {
  bf16x8 r;
  r[0] = (__bf16)a[0]; r[1] = (__bf16)a[1]; r[2] = (__bf16)a[2]; r[3] = (__bf16)a[3];
  r[4] = (__bf16)b[0]; r[5] = (__bf16)b[1]; r[6] = (__bf16)b[2]; r[7] = (__bf16)b[3];
  return r;
}

// load 8 consecutive f32 (16B-aligned x2) and convert to 8 bf16
__device__ __forceinline__ bf16x8 cvt8(const float* __restrict__ p) {
  return cvt8_2(*(const f32x4*)p, *(const f32x4*)(p + 4));
}

// ---------------- K1 v9: partial Gram, global_load_lds f32 staging ----------
// SINGLE change vs R15: DMA width-16 staging straight to LDS (no reg
// round-trip, no staging cvt). Linear LDS dest (gload_lds requirement) +
// pre-swizzled GLOBAL source (chunk ^= row&7, 16B chunks) + same XOR on
// fragment read => 2-way banks. bf16 cvt moved to fragment-read: same RTN
// cast of the same f32 values in the same accumulation order -> bit-identical.
__global__ __launch_bounds__(256, 2) void k1_gram(const float* __restrict__ x,
                                                  __bf16* __restrict__ gpart,
                                                  int kc) {
  const int b = blockIdx.y, chunk = blockIdx.x;
  const float* xb = x + (size_t)b * C_DIM * NTOK + (size_t)chunk * kc;
  __shared__ float xsf[2][C_DIM * 32];  // 2 x 24KB, linear rows of 32 f32
  const int t = threadIdx.x;
  const int lane = t & 63, wid = t >> 6;
  const int lrow = lane & 15, loct = lane >> 4;
  const int r0 = (wid >> 1) * 96, c0 = (wid & 1) * 96;
  const int lx = lrow & 7;
  const int gl_row = 48 * wid + (lane >> 3);          // +8*it per instr
  const int gl_sw = 4 * ((lane & 7) ^ (lane >> 3));   // swizzled 16B-chunk (f32)
  f32x4 acc[6][6] = {};
  const int nst = kc >> 5;  // 16 at nchunk=32

#define K1_GLL(buf, ks_)                                                       \
  {                                                                            \
    _Pragma("unroll") for (int it = 0; it < 6; ++it) {                         \
      const float* g = xb + (size_t)(gl_row + 8 * it) * NTOK + (ks_) + gl_sw;  \
      float* l = &xsf[buf][(48 * wid + 8 * it) * 32 + 4 * lane];               \
      __builtin_amdgcn_global_load_lds(                                        \
          (const __attribute__((address_space(1))) void*)g,                    \
          (__attribute__((address_space(3))) void*)l, 16, 0, 0);               \
    }                                                                          \
  }
#define K1_COMP(buf)                                                           \
  {                                                                            \
    const int c1 = (2 * loct) ^ lx;                                            \
    bf16x8 fa[6];                                                              \
    _Pragma("unroll") for (int i = 0; i < 6; ++i) {                            \
      const float* rb_ = &xsf[buf][(r0 + 16 * i + lrow) * 32];                 \
      fa[i] = cvt8_2(*(const f32x4*)(rb_ + 4 * c1),                            \
                     *(const f32x4*)(rb_ + 4 * (c1 ^ 1)));                     \
    }                                                                          \
    _Pragma("unroll") for (int j = 0; j < 6; ++j) {                            \
      const float* rb_ = &xsf[buf][(c0 + 16 * j + lrow) * 32];                 \
      bf16x8 fb = cvt8_2(*(const f32x4*)(rb_ + 4 * c1),                        \
                         *(const f32x4*)(rb_ + 4 * (c1 ^ 1)));                 \
      _Pragma("unroll") for (int i = 0; i < 6; ++i)                            \
          acc[i][j] = mfma16(fa[i], fb, acc[i][j]);                            \
    }                                                                          \
  }

  K1_GLL(0, 0);
  __syncthreads();  // drains DMA (compiler emits vmcnt(0) before barrier)
  for (int s = 0; s < nst; ++s) {
    const int cur = s & 1;
    if (s + 1 < nst) K1_GLL(cur ^ 1, 32 * (s + 1));  // DMA next slab
    K1_COMP(cur);
    __syncthreads();
  }
#undef K1_GLL
#undef K1_COMP

  if (wid != 2) {  // (96,0) quadrant == transpose of (0,96): not stored
    __bf16* gp = gpart + ((size_t)chunk * NB + b) * C_DIM * C_DIM;
#pragma unroll
    for (int i = 0; i < 6; ++i)
#pragma unroll
      for (int j = 0; j < 6; ++j)
#pragma unroll
        for (int e = 0; e < 4; ++e)
          gp[(size_t)(r0 + 16 * i + 4 * loct + e) * C_DIM + (c0 + 16 * j + lrow)] =
              (__bf16)acc[i][j][e];
  }
}

// ---------------- K2a: reduce bf16 partials -> G (with (96,0) mirror) -------
__global__ __launch_bounds__(256) void k2a_reduce(const __bf16* __restrict__ gpart,
                                                  float* __restrict__ G,
                                                  int nchunk) {
  const int qi = blockIdx.y, b = blockIdx.z;
  const int idx = blockIdx.x * 256 + threadIdx.x;  // < 2304
  const int r = idx / 24, c4 = idx % 24;
  const int r_off = (qi == 2) ? 96 : 0;
  const int c_off = (qi == 0) ? 0 : 96;
  const size_t total = (size_t)NB * C_DIM * C_DIM;
  const size_t base = (size_t)b * C_DIM * C_DIM +
                      (size_t)(r_off + r) * C_DIM + c_off + 4 * c4;
  float s0 = 0.f, s1 = 0.f, s2 = 0.f, s3 = 0.f;
  for (int ch = 0; ch < nchunk; ++ch) {
    bf16x4 v = *(const bf16x4*)(gpart + ch * total + base);
    s0 += (float)v[0]; s1 += (float)v[1]; s2 += (float)v[2]; s3 += (float)v[3];
  }
  float* Gb = G + (size_t)b * C_DIM * C_DIM;
  f32x4 sv; sv[0] = s0; sv[1] = s1; sv[2] = s2; sv[3] = s3;
  *(f32x4*)(Gb + (size_t)(r_off + r) * C_DIM + c_off + 4 * c4) = sv;
  if (qi == 1) {  // mirror (0,96) -> (96,0)
    Gb[(size_t)(96 + 4 * c4 + 0) * C_DIM + r] = s0;
    Gb[(size_t)(96 + 4 * c4 + 1) * C_DIM + r] = s1;
    Gb[(size_t)(96 + 4 * c4 + 2) * C_DIM + r] = s2;
    Gb[(size_t)(96 + 4 * c4 + 3) * C_DIM + r] = s3;
  }
}

// ---------------- K2b fused (R15-proven): per (b,h) T -> S -> softmax -> Yt -
__global__ __launch_bounds__(256) void k2b_fused(const float* __restrict__ G,
                                                 const float* __restrict__ wqkv,
                                                 const float* __restrict__ temp,
                                                 float* __restrict__ Yt) {
  const int h = blockIdx.x, b = blockIdx.y;
  __shared__ float Tl[48 * 196];  // 37.6KB
  __shared__ float SL[32][33];
  __shared__ float qn2L[HD], kn2L[HD];
  const int t = threadIdx.x;
  const int lane = t & 63, wid = t >> 6;
  const int lrow = lane & 15, loct = lane >> 4;
  const float* Gb = G + (size_t)b * C_DIM * C_DIM;

  // ---- Phase 1: Tl[p][:] = wqkv[:, col(p)]^T @ G, p = wid*16 + lrow ----
  if (wid < 3) {
    const int p = wid * 16 + lrow;  // packed row 0..47
    const int col = (p < HD) ? (h * HD + p) : (192 + h * HD + p - HD);
    f32x4 acc[12] = {};
    for (int s = 0; s < 6; ++s) {
      bf16x8 fa;
#pragma unroll
      for (int e = 0; e < 8; ++e)
        fa[e] = (__bf16)wqkv[(size_t)(32 * s + 8 * loct + e) * 576 + col];
#pragma unroll
      for (int j = 0; j < 12; ++j) {
        bf16x8 fb = cvt8(Gb + (size_t)(16 * j + lrow) * C_DIM + 32 * s + 8 * loct);
        acc[j] = mfma16(fa, fb, acc[j]);
      }
    }
#pragma unroll
    for (int j = 0; j < 12; ++j)
#pragma unroll
      for (int e = 0; e < 4; ++e)
        Tl[(wid * 16 + 4 * loct + e) * 196 + 16 * j + lrow] = acc[j][e];
  }
  __syncthreads();

  // ---- Phase 2: S = Tq . Wk_h (packed rows 0..23 are q-rows) ----
  const int r = wid >> 1, j = wid & 1;  // 2x2 tiles cover 32x32 (clip 24x24)
  f32x4 acc = {};
  for (int s = 0; s < 6; ++s) {
    bf16x8 fa = cvt8(&Tl[(16 * r + lrow) * 196 + 32 * s + 8 * loct]);
    bf16x8 fb;
#pragma unroll
    for (int e = 0; e < 8; ++e)
      fb[e] = (__bf16)wqkv[(size_t)(32 * s + 8 * loct + e) * 576 + 192 + h * HD +
                           16 * j + lrow];
    acc = mfma16(fa, fb, acc);
  }
#pragma unroll
  for (int e = 0; e < 4; ++e) {
    int d = 16 * r + 4 * loct + e, ee = 16 * j + lrow;
    if (d < HD && ee < HD) SL[d][ee] = acc[e];
  }
  if (t < 48) {  // squared norms: diag of Wq^T G Wq / Wk^T G Wk
    const int dd = (t < HD) ? t : t - HD;
    const int row = ((t < HD) ? 0 : 192) + h * HD + dd;  // wqkv column
    float s = 0.f;
    for (int c = 0; c < C_DIM; ++c)
      s += Tl[t * 196 + c] * wqkv[(size_t)c * 576 + row];
    if (t < HD) qn2L[dd] = s; else kn2L[dd] = s;
  }
  __syncthreads();
  if (t < HD) {  // softmax row t
    const float tp = temp[h];
    float nq = fmaxf(sqrtf(fmaxf(qn2L[t], 0.f)), EPSN);
    float lg[HD];
    float m = -1e30f;
#pragma unroll
    for (int e = 0; e < HD; ++e) {
      float nk = fmaxf(sqrtf(fmaxf(kn2L[e], 0.f)), EPSN);
      lg[e] = SL[t][e] / (nq * nk) * tp;
      m = fmaxf(m, lg[e]);
    }
    float sum = 0.f;
#pragma unroll
    for (int e = 0; e < HD; ++e) { lg[e] = __expf(lg[e] - m); sum += lg[e]; }
    float inv = 1.f / sum;
#pragma unroll
    for (int e = 0; e < HD; ++e) SL[t][e] = lg[e] * inv;
  }
  __syncthreads();
  if (t < C_DIM) {  // Yt[b][ci=t][h*24+d] = sum_e attn[d][e] * Wv[t][e]
    float wv[HD];
#pragma unroll
    for (int e = 0; e < HD; ++e)
      wv[e] = wqkv[(size_t)t * 576 + 384 + h * HD + e];
    float* Yo = Yt + ((size_t)b * C_DIM + t) * C_DIM + h * HD;
#pragma unroll
    for (int d = 0; d < HD; ++d) {
      float y = 0.f;
#pragma unroll
      for (int e = 0; e < HD; ++e) y += SL[d][e] * wv[e];
      Yo[d] = y;
    }
  }
}

// ---------------- K2c: M[b] = Wproj^T @ Y  (bf16 out) -----------------------
__global__ __launch_bounds__(256) void k2c_m(const float* __restrict__ wproj,
                                             const float* __restrict__ Yt,
                                             __bf16* __restrict__ M) {
  const int b = blockIdx.y, rb = blockIdx.x;  // rb 0..2 -> 64 rows
  const int lane = threadIdx.x & 63, wid = threadIdx.x >> 6;
  const int lrow = lane & 15, loct = lane >> 4;
  const float* Yb = Yt + (size_t)b * C_DIM * C_DIM;
  const int coA = rb * 64 + wid * 16 + lrow;
  f32x4 acc[12] = {};
  for (int s = 0; s < 6; ++s) {
    bf16x8 fa;
#pragma unroll
    for (int e = 0; e < 8; ++e)
      fa[e] = (__bf16)wproj[(size_t)(32 * s + 8 * loct + e) * C_DIM + coA];
#pragma unroll
    for (int j = 0; j < 12; ++j) {
      bf16x8 fb = cvt8(Yb + (size_t)(16 * j + lrow) * C_DIM + 32 * s + 8 * loct);
      acc[j] = mfma16(fa, fb, acc[j]);
    }
  }
  __bf16* Mo = M + (size_t)b * C_DIM * C_DIM;
#pragma unroll
  for (int j = 0; j < 12; ++j)
#pragma unroll
    for (int e = 0; e < 4; ++e)
      Mo[(size_t)(rb * 64 + wid * 16 + 4 * loct + e) * C_DIM + 16 * j + lrow] =
          (__bf16)acc[j][e];
}

// ---------------- K3 v6 (proven 95us): out[b] = M[b] @ x[b] + bias ----------
__global__ __launch_bounds__(256, 3) void k3_out(const float* __restrict__ x,
                                                 const __bf16* __restrict__ M,
                                                 const float* __restrict__ bproj,
                                                 float* __restrict__ out) {
  const int nt = blockIdx.x, half = blockIdx.y, b = blockIdx.z;
  const int rbase = half * 96;
  __shared__ __bf16 Ml[96 * C_DIM];  // 36864B; overlaid by epi after main loop
  __shared__ float biasL[96];
  const int t = threadIdx.x;
  const int lane = t & 63, w = t >> 6;
  const int lrow = lane & 15, loct = lane >> 4;

  const __bf16* Mb = M + (size_t)b * C_DIM * C_DIM + (size_t)rbase * C_DIM;
  for (int i = t; i < 96 * 24; i += 256) {
    int row = i / 24, ch = i % 24;
    bf16x8 v = *(const bf16x8*)(Mb + row * C_DIM + ch * 8);
    *(bf16x8*)(Ml + row * C_DIM + ((ch ^ (row & 7)) * 8)) = v;
  }
  if (t < 96) biasL[t] = bproj[rbase + t];
  __syncthreads();

  const float* xb = x + (size_t)b * C_DIM * NTOK;
  float* ob = out + (size_t)b * C_DIM * NTOK;
  const int n0 = nt * 256 + w * 64;  // wave's 64-token window

  f32x4 acc[6][4] = {};
  f32x4 xs4[8];  // prefetch: slab's 8 channels x 4 consecutive tokens
#pragma unroll
  for (int e = 0; e < 8; ++e)
    xs4[e] = *(const f32x4*)(xb + (size_t)(8 * loct + e) * NTOK + n0 + 4 * lrow);

  for (int s = 0; s < 6; ++s) {
    bf16x8 fb[4];  // fb[nf][e] = x[ch=32s+8loct+e][tok=n0+4*lrow+nf]
#pragma unroll
    for (int nf = 0; nf < 4; ++nf)
#pragma unroll
      for (int e = 0; e < 8; ++e)
        fb[nf][e] = (__bf16)xs4[e][nf];
    if (s < 5) {
#pragma unroll
      for (int e = 0; e < 8; ++e)
        xs4[e] = *(const f32x4*)(xb + (size_t)(32 * (s + 1) + 8 * loct + e) * NTOK +
                                 n0 + 4 * lrow);
    }
#pragma unroll
    for (int tt = 0; tt < 6; ++tt) {
      int rowb = 16 * tt + lrow;
      bf16x8 fa = *(const bf16x8*)(Ml + rowb * C_DIM +
                                   (((4 * s + loct) ^ (rowb & 7)) * 8));
#pragma unroll
      for (int nf = 0; nf < 4; ++nf)
        acc[tt][nf] = mfma16(fa, fb[nf], acc[tt][nf]);
    }
  }

  __syncthreads();  // all waves done reading Ml; safe to overlay epi
  // per-wave transpose buffer: 16 rows x 64 tokens, stride 68 f32
  float* epi_w = (float*)Ml + w * 1088;
#pragma unroll
  for (int tt = 0; tt < 6; ++tt) {
    f32x4 bias4 = *(const f32x4*)(biasL + 16 * tt + 4 * loct);  // rows 4loct+e
#pragma unroll
    for (int e = 0; e < 4; ++e) {
      f32x4 v;
      v[0] = acc[tt][0][e] + bias4[e];
      v[1] = acc[tt][1][e] + bias4[e];
      v[2] = acc[tt][2][e] + bias4[e];
      v[3] = acc[tt][3][e] + bias4[e];  // tokens 4*lrow+0..3 of row 16tt+4loct+e
      *(f32x4*)(epi_w + (4 * loct + e) * 68 + 4 * lrow) = v;
    }
    // wave-local ds_write -> ds_read ordered by program order, no barrier
#pragma unroll
    for (int hh = 0; hh < 4; ++hh) {
      int rr = 4 * hh + loct;
      f32x4 v = *(const f32x4*)(epi_w + rr * 68 + 4 * lrow);
      *(f32x4*)(ob + (size_t)(rbase + 16 * tt + rr) * NTOK + n0 + 4 * lrow) = v;
    }
  }
}

extern "C" void kernel_launch(void* const* d_in, const int* in_sizes, int n_in,
                              void* d_out, int out_size, void* d_ws, size_t ws_size,
                              hipStream_t stream) {
  const float* x = (const float*)d_in[0];
  const float* wqkv = (const float*)d_in[1];
  const float* wproj = (const float*)d_in[2];
  const float* bproj = (const float*)d_in[3];
  const float* temp = (const float*)d_in[4];
  float* out = (float*)d_out;

  const size_t GSZ = (size_t)NB * C_DIM * C_DIM;  // 589824 elems
  int nchunk = 32;
  while (nchunk > 1 &&
         (size_t)nchunk * GSZ * 2 + GSZ * 4 + GSZ * 4 + GSZ * 2 > ws_size)
    nchunk >>= 1;
  __bf16* gpart = (__bf16*)d_ws;
  float* G = (float*)(gpart + (size_t)nchunk * GSZ);
  float* Yt = G + GSZ;
  __bf16* M = (__bf16*)(Yt + GSZ);

  k1_gram<<<dim3(nchunk, NB), 256, 0, stream>>>(x, gpart, NTOK / nchunk);
  k2a_reduce<<<dim3(9, 3, NB), 256, 0, stream>>>(gpart, G, nchunk);
  k2b_fused<<<dim3(NH, NB), 256, 0, stream>>>(G, wqkv, temp, Yt);
  k2c_m<<<dim3(3, NB), 256, 0, stream>>>(wproj, Yt, M);
  k3_out<<<dim3(NTOK / 256, 2, NB), 256, 0, stream>>>(x, M, bproj, out);
}